// Round 11
// baseline (1219.299 us; speedup 1.0000x reference)
//
#include <hip/hip_runtime.h>
#include <hip/hip_bf16.h>

typedef __bf16 bf16;
typedef __bf16 bf16x8 __attribute__((ext_vector_type(8)));
typedef float f32x4 __attribute__((ext_vector_type(4)));

#define B_    2
#define L_    2048
#define DM_   2048
#define DI_   4096
#define NST   64
#define PD    64
#define NH    64
#define CONV_ 4224
#define XBCD_ 4288            // CONV_ + NH  (xBC + dt columns)
#define PROJ_ 8384
#define BL_   (B_ * L_)
#define NCHUNK 32             // L_ / 64
#define EPS_  1e-6f

#define WAITV(n) asm volatile("s_waitcnt vmcnt(" #n ")" ::: "memory")
#define LGKM0()  asm volatile("s_waitcnt lgkmcnt(0)" ::: "memory")
#define BAR()    __builtin_amdgcn_s_barrier()

// ---------------------------------------------------------------- reductions
__device__ __forceinline__ float block_reduce_sum_256(float v) {
  #pragma unroll
  for (int m = 32; m; m >>= 1) v += __shfl_xor(v, m, 64);
  __shared__ float sred[4];
  int w = threadIdx.x >> 6;
  if ((threadIdx.x & 63) == 0) sred[w] = v;
  __syncthreads();
  return sred[0] + sred[1] + sred[2] + sred[3];
}

__device__ __forceinline__ float silu_f(float x) {
  return x / (1.0f + expf(-x));
}

// async global->LDS, 16B per lane. LDS dest is wave-uniform base; HW adds
// lane*16. [m97/m104 semantics]
__device__ __forceinline__ void async16(const bf16* g, bf16* l) {
  __builtin_amdgcn_global_load_lds(
      (__attribute__((address_space(1))) void*)g,
      (__attribute__((address_space(3))) void*)l, 16, 0, 0);
}

// ---------------------------------------------------------------- RMSNorm in
__global__ __launch_bounds__(256) void rmsnorm_in_kernel(
    const float* __restrict__ u, const float* __restrict__ w, bf16* __restrict__ hs) {
  int row = blockIdx.x;
  const float* x = u + (size_t)row * DM_;
  int base = threadIdx.x * 8;
  f32x4 v0 = *(const f32x4*)(x + base);
  f32x4 v1 = *(const f32x4*)(x + base + 4);
  float xv[8], ss = 0.f;
  #pragma unroll
  for (int i = 0; i < 4; i++) { xv[i] = v0[i]; xv[4 + i] = v1[i]; }
  #pragma unroll
  for (int i = 0; i < 8; i++) ss += xv[i] * xv[i];
  ss = block_reduce_sum_256(ss);
  float r = rsqrtf(ss / (float)DM_ + EPS_);
  f32x4 w0 = *(const f32x4*)(w + base);
  f32x4 w1 = *(const f32x4*)(w + base + 4);
  bf16x8 o;
  #pragma unroll
  for (int i = 0; i < 4; i++) { o[i] = (bf16)(w0[i] * xv[i] * r); o[4 + i] = (bf16)(w1[i] * xv[4 + i] * r); }
  *(bf16x8*)(hs + (size_t)row * DM_ + base) = o;
}

// ---------------------------------------------------------------- weight f32->bf16
__global__ __launch_bounds__(256) void convert_w_kernel(
    const float* __restrict__ src, bf16* __restrict__ dst,
    long n_src, long n_dst) {
  long e = ((long)blockIdx.x * 256 + threadIdx.x) * 8;
  if (e >= n_dst) return;
  bf16x8 o;
  if (e < n_src) {
    f32x4 a = *(const f32x4*)(src + e);
    f32x4 b = *(const f32x4*)(src + e + 4);
    #pragma unroll
    for (int q = 0; q < 4; q++) { o[q] = (bf16)a[q]; o[4 + q] = (bf16)b[q]; }
  } else {
    #pragma unroll
    for (int q = 0; q < 8; q++) o[q] = (bf16)0.f;
  }
  *(bf16x8*)(dst + e) = o;
}

// ---------------------------------------------------------------- NT GEMM (single-buffer, in-iter prefetch)
// C[M][N] = A[M][K].W[N][K]^T, bf16 in. 128x128 tile, BK=64, 4 waves (2x2),
// 32 KB LDS -> ~5 blocks/CU residency. After the 16 fragment reads complete
// (lgkmcnt(0) + barrier), the LDS tile is dead for the rest of the iter, so
// tile t+1 is staged into the SAME buffer BEFORE the MFMA burst — the 32
// MFMAs (~154cy) cover the L2 latency, and the loop-top vmcnt(0) waits only
// the residual (T14 issue-early/write-late). XOR slot swizzle as before.
template <bool OUT_F32>
__global__ __launch_bounds__(256, 4) void gemm_nt_sp(
    const bf16* __restrict__ A, int lda,
    const bf16* __restrict__ W, int ldw,
    void* __restrict__ Cout, int ldc, const float* __restrict__ resid,
    int N, int K) {
  __shared__ __align__(16) bf16 As[128 * 64];
  __shared__ __align__(16) bf16 Bs[128 * 64];
  // bijective XCD swizzle (m204)
  int nwg = gridDim.x * gridDim.y;
  int bid = blockIdx.y * gridDim.x + blockIdx.x;
  int q8 = nwg >> 3, r8 = nwg & 7;
  int xcd = bid & 7, loc = bid >> 3;
  int nb = (xcd < r8 ? xcd * (q8 + 1) : r8 * (q8 + 1) + (xcd - r8) * q8) + loc;
  int bn = nb % gridDim.x, bm = nb / gridDim.x;
  int m0 = bm * 128, n0 = bn * 128;
  int tid = threadIdx.x, wave = tid >> 6, lane = tid & 63;
  int wm = (wave >> 1) * 64, wn = (wave & 1) * 64;
  int lm = lane & 15, lk = (lane >> 4) * 8;
  int lr = lane >> 3;                  // row within 8-row chunk
  int cse = ((lane & 7) ^ lr) * 8;     // pre-swizzled source slot
  f32x4 acc[4][4] = {};

  auto stage = [&](int t) {
    #pragma unroll
    for (int i = 0; i < 4; ++i) {
      int row = (wave * 4 + i) * 8;    // 16 chunks of 8 rows; 4 per wave
      async16(A + (size_t)(m0 + row + lr) * lda + t * 64 + cse, &As[row * 64]);
      async16(W + (size_t)(n0 + row + lr) * ldw + t * 64 + cse, &Bs[row * 64]);
    }
  };

  int NT = K / 64;
  stage(0);
  for (int t = 0; t < NT; ++t) {
    WAITV(0);                          // residual latency only (covered below)
    BAR();                             // tile t published to all waves
    bf16x8 af[4], bf[4];
    #pragma unroll
    for (int i = 0; i < 4; ++i) {
      int row = wm + i * 16 + lm;
      af[i] = *(const bf16x8*)&As[row * 64 + ((((0 + lk) >> 3) ^ (row & 7)) << 3)];
    }
    #pragma unroll
    for (int j = 0; j < 4; ++j) {
      int row = wn + j * 16 + lm;
      bf[j] = *(const bf16x8*)&Bs[row * 64 + ((((0 + lk) >> 3) ^ (row & 7)) << 3)];
    }
    bf16x8 af2[4], bf2[4];
    #pragma unroll
    for (int i = 0; i < 4; ++i) {
      int row = wm + i * 16 + lm;
      af2[i] = *(const bf16x8*)&As[row * 64 + ((((32 + lk) >> 3) ^ (row & 7)) << 3)];
    }
    #pragma unroll
    for (int j = 0; j < 4; ++j) {
      int row = wn + j * 16 + lm;
      bf2[j] = *(const bf16x8*)&Bs[row * 64 + ((((32 + lk) >> 3) ^ (row & 7)) << 3)];
    }
    LGKM0();                           // all 16 reads in registers
    BAR();                             // every wave done reading -> LDS dead
    if (t + 1 < NT) stage(t + 1);      // overwrite same buffer; lands by next WAITV
    #pragma unroll
    for (int i = 0; i < 4; ++i)
      #pragma unroll
      for (int j = 0; j < 4; ++j)
        acc[i][j] = __builtin_amdgcn_mfma_f32_16x16x32_bf16(af[i], bf[j], acc[i][j], 0, 0, 0);
    #pragma unroll
    for (int i = 0; i < 4; ++i)
      #pragma unroll
      for (int j = 0; j < 4; ++j)
        acc[i][j] = __builtin_amdgcn_mfma_f32_16x16x32_bf16(af2[i], bf2[j], acc[i][j], 0, 0, 0);
  }
  // ---- epilogue
  int r0 = m0 + wm + (lane >> 4) * 4;
  #pragma unroll
  for (int i = 0; i < 4; ++i) {
    #pragma unroll
    for (int j = 0; j < 4; ++j) {
      int col = n0 + wn + j * 16 + lm;
      if (col < N) {
        #pragma unroll
        for (int r = 0; r < 4; ++r) {
          int row = r0 + i * 16 + r;
          size_t idx = (size_t)row * ldc + col;
          float v = acc[i][j][r];
          if (resid) v += resid[idx];
          if (OUT_F32) ((float*)Cout)[idx] = v;
          else         ((bf16*)Cout)[idx]  = (bf16)v;
        }
      }
    }
  }
}

// ---------------------------------------------------------------- conv1d+SiLU (B/C cols only)
__global__ __launch_bounds__(256) void conv_bc_kernel(
    const bf16* __restrict__ xbcdt, const float* __restrict__ cw,
    const float* __restrict__ cb, bf16* __restrict__ xc) {
  int idx = blockIdx.x * 256 + threadIdx.x;
  if (idx >= BL_ * 16) return;          // 128 B/C cols / 8
  int c8 = idx & 15, t = idx >> 4;
  int l = t % L_;
  int c = DI_ + c8 * 8;
  float acc[8];
  f32x4 bv0 = *(const f32x4*)(cb + c);
  f32x4 bv1 = *(const f32x4*)(cb + c + 4);
  #pragma unroll
  for (int q = 0; q < 4; q++) { acc[q] = bv0[q]; acc[4 + q] = bv1[q]; }
  #pragma unroll
  for (int k = 0; k < 4; k++) {
    int ls = l + k - 3;
    if (ls >= 0) {
      const bf16* xp = xbcdt + (size_t)(t + k - 3) * XBCD_ + c;
      bf16x8 xv = *(const bf16x8*)xp;
      f32x4 wv0 = *(const f32x4*)(cw + k * CONV_ + c);
      f32x4 wv1 = *(const f32x4*)(cw + k * CONV_ + c + 4);
      #pragma unroll
      for (int q = 0; q < 4; q++) { acc[q] += (float)xv[q] * wv0[q]; acc[4 + q] += (float)xv[4 + q] * wv1[q]; }
    }
  }
  bf16x8 o;
  #pragma unroll
  for (int q = 0; q < 8; q++) o[q] = (bf16)silu_f(acc[q]);
  *(bf16x8*)(xc + (size_t)t * CONV_ + c) = o;
}

// ---------------------------------------------------------------- dt (softplus)
__global__ __launch_bounds__(256) void dt_kernel(
    const bf16* __restrict__ xbcdt, const float* __restrict__ dt_bias,
    float* __restrict__ dtH) {
  int idx = blockIdx.x * 256 + threadIdx.x;
  if (idx >= BL_ * NH) return;
  int h = idx & 63, t = idx >> 6;
  float raw = (float)xbcdt[(size_t)t * XBCD_ + CONV_ + h] + dt_bias[h];
  float v = (raw > 20.f) ? raw : log1pf(expf(raw));
  dtH[(size_t)h * BL_ + t] = v;
}

// ---------------------------------------------------------------- Atot precompute
__global__ __launch_bounds__(256) void atot_kernel(
    const float* __restrict__ dtH, const float* __restrict__ A_log,
    float* __restrict__ Atot) {
  int idx = blockIdx.x * 256 + threadIdx.x;
  if (idx >= B_ * NH * NCHUNK) return;
  int c = idx & 31, rem = idx >> 5;
  int h = rem & 63, b = rem >> 6;
  const float* p = dtH + (size_t)h * BL_ + b * L_ + c * 64;
  float s = 0.f;
  #pragma unroll 8
  for (int i = 0; i < 64; i++) s += p[i];
  Atot[idx] = expf(-expf(A_log[h]) * s);
}

// ---------------------------------------------------------------- scan pass 1 (MFMA SSD, fused x-conv)
__global__ __launch_bounds__(256) void scan_chunk_mfma(
    bf16* __restrict__ xc, const bf16* __restrict__ xbcdt,
    const float* __restrict__ cw, const float* __restrict__ cb,
    const float* __restrict__ dtH,
    const float* __restrict__ A_log, const float* __restrict__ Dp,
    bf16* __restrict__ Sc) {
  __shared__ bf16 Bs[64][72];   // B rows s, cols n   (swizzled)
  __shared__ bf16 Cs[64][72];   // C rows t, cols n   (natural)
  __shared__ bf16 Xt[64][72];   // x^T rows p, cols s (swizzled)
  __shared__ bf16 Gh[64][72];   // masked G hi  [t][s], later wB hi [n][s]
  __shared__ bf16 Gl[64][72];   // masked G lo  [t][s], later wB lo [n][s]
  __shared__ float dts[64];
  __shared__ float cum[64];
  __shared__ float wsA[64];
  int bi = blockIdx.x;
  int h = bi & 63, c = (bi >> 6) & 31, b = bi >> 11;
  int tid = threadIdx.x;
  int wave = tid >> 6, lane = tid & 63;
  int lm = lane & 15, lk = (lane >> 4) * 8;
  int cl = lane & 15, rw4 = (lane >> 4) * 4;
  int wt = (wave >> 1) * 32, wq = (wave & 1) * 32;
  size_t rowbase = (size_t)b * L_ + c * 64;
  float aA = expf(A_log[h]);
  // ---- stage: x via fused conv (registers), B (swizzled), C (natural)
  #pragma unroll
  for (int i = 0; i < 2; i++) {
    int cc = tid + i * 256;
    int s = cc >> 3, e8 = (cc & 7) * 8;
    const bf16* base = xc + (rowbase + s) * CONV_;
    bf16x8 bv = *(const bf16x8*)(base + DI_ + e8);
    bf16x8 cv = *(const bf16x8*)(base + DI_ + NST + e8);
    *(bf16x8*)&Bs[s][e8 ^ (s & 56)] = bv;
    *(bf16x8*)&Cs[s][e8] = cv;
    // fused depthwise conv + SiLU for x columns h*PD + e8 .. +7
    int col = h * PD + e8;
    int l = c * 64 + s;
    float acc[8];
    f32x4 cb0 = *(const f32x4*)(cb + col);
    f32x4 cb1 = *(const f32x4*)(cb + col + 4);
    #pragma unroll
    for (int q = 0; q < 4; q++) { acc[q] = cb0[q]; acc[4 + q] = cb1[q]; }
    #pragma unroll
    for (int k = 0; k < 4; k++) {
      int ls = l + k - 3;
      if (ls >= 0) {
        const bf16* xp = xbcdt + (rowbase + s + k - 3) * XBCD_ + col;
        bf16x8 xv = *(const bf16x8*)xp;
        f32x4 wv0 = *(const f32x4*)(cw + k * CONV_ + col);
        f32x4 wv1 = *(const f32x4*)(cw + k * CONV_ + col + 4);
        #pragma unroll
        for (int q = 0; q < 4; q++) { acc[q] += (float)xv[q] * wv0[q]; acc[4 + q] += (float)xv[4 + q] * wv1[q]; }
      }
    }
    #pragma unroll
    for (int q = 0; q < 8; q++) Xt[e8 + q][s ^ e8] = (bf16)silu_f(acc[q]);
  }
  if (tid < 64) dts[tid] = dtH[(size_t)h * BL_ + rowbase + tid];
  __syncthreads();
  // ---- inclusive prefix sum of dt (wave 0)
  if (tid < 64) {
    float v = dts[tid];
    #pragma unroll
    for (int off = 1; off < 64; off <<= 1) {
      float o = __shfl_up(v, off, 64);
      if (tid >= off) v += o;
    }
    cum[tid] = v;
  }
  __syncthreads();
  if (tid < 64) wsA[tid] = expf(-aA * (cum[63] - cum[tid])) * dts[tid];
  // ---- G[t][s] = sum_n C[t][n] * B[s][n]
  f32x4 gacc[2][2] = {};
  #pragma unroll
  for (int ks = 0; ks < 64; ks += 32) {
    bf16x8 af[2], bfr[2];
    #pragma unroll
    for (int i = 0; i < 2; i++) af[i] = *(bf16x8*)&Cs[wt + i * 16 + lm][ks + lk];
    #pragma unroll
    for (int j = 0; j < 2; j++) {
      int S = wq + j * 16 + lm;
      bfr[j] = *(bf16x8*)&Bs[S][(ks + lk) ^ (S & 56)];
    }
    #pragma unroll
    for (int i = 0; i < 2; i++)
      #pragma unroll
      for (int j = 0; j < 2; j++)
        gacc[i][j] = __builtin_amdgcn_mfma_f32_16x16x32_bf16(af[i], bfr[j], gacc[i][j], 0, 0, 0);
  }
  // ---- causal decay mask, hi/lo split -> Gh/Gl [t][s]
  #pragma unroll
  for (int i = 0; i < 2; i++) {
    #pragma unroll
    for (int j = 0; j < 2; j++) {
      #pragma unroll
      for (int r = 0; r < 4; r++) {
        int t = wt + i * 16 + rw4 + r;
        int s = wq + j * 16 + cl;
        float g = 0.f;
        if (s <= t) g = gacc[i][j][r] * expf(-aA * (cum[t] - cum[s])) * dts[s];
        bf16 ghi = (bf16)g;
        Gh[t][s] = ghi;
        Gl[t][s] = (bf16)(g - (float)ghi);
      }
    }
  }
  __syncthreads();
  // ---- Y[t][p] = sum_s Gm[t][s] * x_s[p];  + D*x; write into xc x-region
  f32x4 yacc[2][2] = {};
  #pragma unroll
  for (int ks = 0; ks < 64; ks += 32) {
    bf16x8 ah[2], al[2], bx[2];
    #pragma unroll
    for (int i = 0; i < 2; i++) {
      ah[i] = *(bf16x8*)&Gh[wt + i * 16 + lm][ks + lk];
      al[i] = *(bf16x8*)&Gl[wt + i * 16 + lm][ks + lk];
    }
    #pragma unroll
    for (int j = 0; j < 2; j++) {
      int P = wq + j * 16 + lm;
      bx[j] = *(bf16x8*)&Xt[P][(ks + lk) ^ (P & 56)];
    }
    #pragma unroll
    for (int i = 0; i < 2; i++)
      #pragma unroll
      for (int j = 0; j < 2; j++) {
        yacc[i][j] = __builtin_amdgcn_mfma_f32_16x16x32_bf16(ah[i], bx[j], yacc[i][j], 0, 0, 0);
        yacc[i][j] = __builtin_amdgcn_mfma_f32_16x16x32_bf16(al[i], bx[j], yacc[i][j], 0, 0, 0);
      }
  }
  float Dv = Dp[h];
  #pragma unroll
  for (int i = 0; i < 2; i++) {
    #pragma unroll
    for (int j = 0; j < 2; j++) {
      int p = wq + j * 16 + cl;
      #pragma unroll
      for (int r = 0; r < 4; r++) {
        int t = wt + i * 16 + rw4 + r;
        float yv = yacc[i][j][r] + Dv * (float)Xt[p][t ^ (p & 56)];
        xc[(rowbase + t) * CONV_ + h * PD + p] = (bf16)yv;
      }
    }
  }
  __syncthreads();
  // ---- wB[n][s] = w_s * B_s[n], hi/lo into Gh/Gl (reuse buffers)
  #pragma unroll
  for (int i = 0; i < 2; i++) {
    int cc = tid + i * 256;
    int n = cc >> 3, s8 = (cc & 7) * 8;
    bf16x8 vh, vl;
    #pragma unroll
    for (int q = 0; q < 8; q++) {
      int s = s8 + q;
      float wb = (float)Bs[s][n ^ (s & 56)] * wsA[s];
      vh[q] = (bf16)wb;
      vl[q] = (bf16)(wb - (float)vh[q]);
    }
    *(bf16x8*)&Gh[n][s8] = vh;
    *(bf16x8*)&Gl[n][s8] = vl;
  }
  __syncthreads();
  // ---- S[p][n] = sum_s x_s[p] * wB[n][s]; write Sc
  f32x4 sacc[2][2] = {};
  #pragma unroll
  for (int ks = 0; ks < 64; ks += 32) {
    bf16x8 ax[2], bh[2], bl[2];
    #pragma unroll
    for (int i = 0; i < 2; i++) {
      int P = wt + i * 16 + lm;
      ax[i] = *(bf16x8*)&Xt[P][(ks + lk) ^ (P & 56)];
    }
    #pragma unroll
    for (int j = 0; j < 2; j++) {
      bh[j] = *(bf16x8*)&Gh[wq + j * 16 + lm][ks + lk];
      bl[j] = *(bf16x8*)&Gl[wq + j * 16 + lm][ks + lk];
    }
    #pragma unroll
    for (int i = 0; i < 2; i++)
      #pragma unroll
      for (int j = 0; j < 2; j++) {
        sacc[i][j] = __builtin_amdgcn_mfma_f32_16x16x32_bf16(ax[i], bh[j], sacc[i][j], 0, 0, 0);
        sacc[i][j] = __builtin_amdgcn_mfma_f32_16x16x32_bf16(ax[i], bl[j], sacc[i][j], 0, 0, 0);
      }
  }
  bf16* scp = Sc + ((((size_t)b * NCHUNK + c) * NH + h) << 12);
  #pragma unroll
  for (int i = 0; i < 2; i++) {
    #pragma unroll
    for (int j = 0; j < 2; j++) {
      int n = wq + j * 16 + cl;
      #pragma unroll
      for (int r = 0; r < 4; r++) {
        int p = wt + i * 16 + rw4 + r;
        scp[p * 64 + n] = (bf16)sacc[i][j][r];
      }
    }
  }
}

// ---------------------------------------------------------------- scan pass 2 (element-parallel)
__global__ __launch_bounds__(256) void state_scan_kernel(
    bf16* __restrict__ Sc, const float* __restrict__ Atot) {
  __shared__ float At[NCHUNK];
  int bid = blockIdx.x;
  int seg = bid & 15, rem = bid >> 4;          // rem = b*64 + h
  int e = seg * 256 + threadIdx.x;             // element in [0,4096)
  if (threadIdx.x < NCHUNK) At[threadIdx.x] = Atot[(rem << 5) + threadIdx.x];
  __syncthreads();
  int h = rem & 63, b = rem >> 6;
  bf16* p = Sc + ((((size_t)b * NCHUNK) * NH + h) << 12) + e;
  const size_t cstride = (size_t)NH << 12;
  float H = 0.f;
  #pragma unroll 4
  for (int c = 0; c < NCHUNK; ++c) {
    float s = (float)*p;
    *p = (bf16)H;                              // h_prev for chunk c
    H = At[c] * H + s;
    p += cstride;
  }
}

// ---------------------------------------------------------------- scan pass 3 (MFMA)
__global__ __launch_bounds__(256) void y_inter_mfma(
    bf16* __restrict__ xc, const float* __restrict__ dtH,
    const float* __restrict__ A_log, const bf16* __restrict__ Sc) {
  __shared__ bf16 Cs[64][72];
  __shared__ bf16 Hs[64][72];
  __shared__ float dts[64];
  __shared__ float eA[64];
  int bi = blockIdx.x;
  int h = bi & 63, c = (bi >> 6) & 31, b = bi >> 11;
  int tid = threadIdx.x;
  int wave = tid >> 6, lane = tid & 63;
  int lm = lane & 15, lk = (lane >> 4) * 8;
  int cl = lane & 15, rw4 = (lane >> 4) * 4;
  int wt = (wave >> 1) * 32, wp = (wave & 1) * 32;
  size_t rowbase = (size_t)b * L_ + c * 64;
  float aA = expf(A_log[h]);
  const bf16* scp = Sc + ((((size_t)b * NCHUNK + c) * NH + h) << 12);
  #pragma unroll
  for (int i = 0; i < 2; i++) {
    int cc = tid + i * 256;
    int s = cc >> 3, e8 = (cc & 7) * 8;
    bf16x8 cv = *(const bf16x8*)(xc + (rowbase + s) * CONV_ + DI_ + NST + e8);
    *(bf16x8*)&Cs[s][e8] = cv;
  }
  {
    int p = tid >> 2, n16 = (tid & 3) * 16;
    *(bf16x8*)&Hs[p][n16]     = *(const bf16x8*)(scp + p * 64 + n16);
    *(bf16x8*)&Hs[p][n16 + 8] = *(const bf16x8*)(scp + p * 64 + n16 + 8);
  }
  if (tid < 64) dts[tid] = dtH[(size_t)h * BL_ + rowbase + tid];
  __syncthreads();
  if (tid < 64) {
    float v = dts[tid];
    #pragma unroll
    for (int off = 1; off < 64; off <<= 1) {
      float o = __shfl_up(v, off, 64);
      if (tid >= off) v += o;
    }
    eA[tid] = expf(-aA * v);
  }
  __syncthreads();
  f32x4 acc[2][2] = {};
  #pragma unroll
  for (int ks = 0; ks < 64; ks += 32) {
    bf16x8 af[2], bfr[2];
    #pragma unroll
    for (int i = 0; i < 2; i++) af[i]  = *(bf16x8*)&Cs[wt + i * 16 + lm][ks + lk];
    #pragma unroll
    for (int j = 0; j < 2; j++) bfr[j] = *(bf16x8*)&Hs[wp + j * 16 + lm][ks + lk];
    #pragma unroll
    for (int i = 0; i < 2; i++)
      #pragma unroll
      for (int j = 0; j < 2; j++)
        acc[i][j] = __builtin_amdgcn_mfma_f32_16x16x32_bf16(af[i], bfr[j], acc[i][j], 0, 0, 0);
  }
  #pragma unroll
  for (int i = 0; i < 2; i++) {
    #pragma unroll
    for (int j = 0; j < 2; j++) {
      int p = wp + j * 16 + cl;
      #pragma unroll
      for (int r = 0; r < 4; r++) {
        int t = wt + i * 16 + rw4 + r;
        size_t gi = (rowbase + t) * CONV_ + h * PD + p;
        xc[gi] = (bf16)((float)xc[gi] + eA[t] * acc[i][j][r]);
      }
    }
  }
}

// ---------------------------------------------------------------- gated RMSNorm
__global__ __launch_bounds__(256) void gated_norm_kernel(
    const bf16* __restrict__ xc, bf16* __restrict__ zbuf,
    const float* __restrict__ nw) {
  int t = blockIdx.x;
  int base = threadIdx.x * 16;
  const bf16* yr = xc + (size_t)t * CONV_;
  bf16* zr = zbuf + (size_t)t * DI_;
  float tv[16], ss = 0.f;
  #pragma unroll
  for (int i8 = 0; i8 < 2; i8++) {
    bf16x8 yv = *(const bf16x8*)(yr + base + i8 * 8);
    bf16x8 zv = *(const bf16x8*)(zr + base + i8 * 8);
    #pragma unroll
    for (int q = 0; q < 8; q++) {
      float tt = (float)yv[q] * silu_f((float)zv[q]);
      tv[i8 * 8 + q] = tt;
      ss += tt * tt;
    }
  }
  ss = block_reduce_sum_256(ss);
  float r = rsqrtf(ss / (float)DI_ + EPS_);
  #pragma unroll
  for (int i8 = 0; i8 < 2; i8++) {
    f32x4 w0 = *(const f32x4*)(nw + base + i8 * 8);
    f32x4 w1 = *(const f32x4*)(nw + base + i8 * 8 + 4);
    bf16x8 o;
    #pragma unroll
    for (int q = 0; q < 4; q++) {
      o[q]     = (bf16)(w0[q] * tv[i8 * 8 + q] * r);
      o[4 + q] = (bf16)(w1[q] * tv[i8 * 8 + 4 + q] * r);
    }
    *(bf16x8*)(zr + base + i8 * 8) = o;
  }
}

// ---------------------------------------------------------------- ws diagnostic
__global__ void ws_report_kernel(float* out, float ws_mb) {
  if (blockIdx.x == 0 && threadIdx.x == 0) out[0] = ws_mb;
}

// ---------------------------------------------------------------- launch
extern "C" void kernel_launch(void* const* d_in, const int* in_sizes, int n_in,
                              void* d_out, int out_size, void* d_ws, size_t ws_size,
                              hipStream_t stream) {
  const float* u        = (const float*)d_in[0];
  const float* ln_w     = (const float*)d_in[1];
  const float* in_proj  = (const float*)d_in[2];
  const float* conv_w   = (const float*)d_in[3];
  const float* conv_b   = (const float*)d_in[4];
  const float* dt_bias  = (const float*)d_in[5];
  const float* A_log    = (const float*)d_in[6];
  const float* Dp       = (const float*)d_in[7];
  const float* norm_w   = (const float*)d_in[8];
  const float* out_proj = (const float*)d_in[9];
  float* out = (float*)d_out;

  bf16* hs = (bf16*)d_out;     // scratch inside d_out (dead before final GEMM)

  char* ws = (char*)d_ws;
  size_t off = 0;
  auto alloc = [&](size_t bytes) { char* p = ws + off; off = (off + bytes + 255) & ~(size_t)255; return p; };
  float* dtH  = (float*)alloc((size_t)BL_ * NH * 4);          //  1.05 MB  [h][b*L+t]
  float* Atot = (float*)alloc((size_t)B_ * NH * NCHUNK * 4);  //  16 KB
  bf16*  wbuf = (bf16*)alloc((size_t)4352 * DM_ * 2);         // 17.8 MB bf16 weight slice
  bf16*  shbuf= (bf16*)alloc((size_t)BL_ * XBCD_ * 2);        // 35.1 MB (xbcdt → zbuf)
  bf16*  xc   = (bf16*)alloc((size_t)BL_ * CONV_ * 2);        // 34.6 MB
  bf16*  Sc   = (bf16*)alloc((size_t)B_ * NCHUNK * NH * 64 * 64 * 2);  // 32 MB
  size_t need = off;                                          // ~120.6 MB

  if (ws_size < need) {
    ws_report_kernel<<<1, 64, 0, stream>>>(out, (float)(ws_size >> 20));
    return;
  }

  bf16* xbcdt = shbuf;          // phase 1: BL x XBCD_  (live through scan pass 1)
  bf16* zbuf  = shbuf;          // phase 3: BL x DI_

  rmsnorm_in_kernel<<<BL_, 256, 0, stream>>>(u, ln_w, hs);

  // GEMM1: zxbcdt tail (xBC + dt), weights padded to 4352 rows.
  {
    long nsrc = (long)XBCD_ * DM_, ndst = (long)4352 * DM_;
    convert_w_kernel<<<(int)(ndst / 8 / 256), 256, 0, stream>>>(
        in_proj + (size_t)DI_ * DM_, wbuf, nsrc, ndst);
    gemm_nt_sp<false><<<dim3(4352 / 128, BL_ / 128), 256, 0, stream>>>(
        hs, DM_, wbuf, DM_, xbcdt, XBCD_, nullptr, XBCD_, DM_);
  }
  conv_bc_kernel<<<(BL_ * 16 + 255) / 256, 256, 0, stream>>>(
      xbcdt, conv_w, conv_b, xc);
  dt_kernel<<<(BL_ * NH + 255) / 256, 256, 0, stream>>>(
      xbcdt, dt_bias, dtH);
  atot_kernel<<<(B_ * NH * NCHUNK + 255) / 256, 256, 0, stream>>>(
      dtH, A_log, Atot);
  // chunked SSD scan with fused x-conv (xbcdt still live)
  scan_chunk_mfma<<<B_ * NH * NCHUNK, 256, 0, stream>>>(
      xc, xbcdt, conv_w, conv_b, dtH, A_log, Dp, Sc);
  state_scan_kernel<<<B_ * NH * 16, 256, 0, stream>>>(Sc, Atot);
  y_inter_mfma<<<B_ * NH * NCHUNK, 256, 0, stream>>>(xc, dtH, A_log, Sc);

  // GEMM2: z part of in_proj (xbcdt dead; shbuf becomes zbuf)
  {
    long n = (long)DI_ * DM_;
    convert_w_kernel<<<(int)(n / 8 / 256), 256, 0, stream>>>(in_proj, wbuf, n, n);
    gemm_nt_sp<false><<<dim3(DI_ / 128, BL_ / 128), 256, 0, stream>>>(
        hs, DM_, wbuf, DM_, zbuf, DI_, nullptr, DI_, DM_);
  }
  gated_norm_kernel<<<BL_, 256, 0, stream>>>(xc, zbuf, norm_w);

  // GEMM3: out projection + residual
  {
    long n = (long)DM_ * DI_;
    convert_w_kernel<<<(int)(n / 8 / 256), 256, 0, stream>>>(out_proj, wbuf, n, n);
    gemm_nt_sp<true><<<dim3(DM_ / 128, BL_ / 128), 256, 0, stream>>>(
        zbuf, DI_, wbuf, DI_, out, DM_, u, DM_, DI_);
  }
}

// Round 12
// 573.828 us; speedup vs baseline: 2.1249x; 2.1249x over previous
//
#include <hip/hip_runtime.h>
#include <hip/hip_bf16.h>

typedef __bf16 bf16;
typedef __bf16 bf16x8 __attribute__((ext_vector_type(8)));
typedef float f32x4 __attribute__((ext_vector_type(4)));

#define B_    2
#define L_    2048
#define DM_   2048
#define DI_   4096
#define NST   64
#define PD    64
#define NH    64
#define CONV_ 4224
#define XBCD_ 4288            // CONV_ + NH  (xBC + dt columns)
#define PROJ_ 8384
#define BL_   (B_ * L_)
#define NCHUNK 32             // L_ / 64
#define EPS_  1e-6f

#define WAITV(n) asm volatile("s_waitcnt vmcnt(" #n ")" ::: "memory")
#define BAR()    __builtin_amdgcn_s_barrier()

// ---------------------------------------------------------------- reductions
__device__ __forceinline__ float block_reduce_sum_256(float v) {
  #pragma unroll
  for (int m = 32; m; m >>= 1) v += __shfl_xor(v, m, 64);
  __shared__ float sred[4];
  int w = threadIdx.x >> 6;
  if ((threadIdx.x & 63) == 0) sred[w] = v;
  __syncthreads();
  return sred[0] + sred[1] + sred[2] + sred[3];
}

__device__ __forceinline__ float silu_f(float x) {
  return x / (1.0f + expf(-x));
}

// async global->LDS, 16B per lane. LDS dest is wave-uniform base; HW adds
// lane*16. [m97/m104 semantics]
__device__ __forceinline__ void async16(const bf16* g, bf16* l) {
  __builtin_amdgcn_global_load_lds(
      (__attribute__((address_space(1))) void*)g,
      (__attribute__((address_space(3))) void*)l, 16, 0, 0);
}

// ---------------------------------------------------------------- RMSNorm in
__global__ __launch_bounds__(256) void rmsnorm_in_kernel(
    const float* __restrict__ u, const float* __restrict__ w, bf16* __restrict__ hs) {
  int row = blockIdx.x;
  const float* x = u + (size_t)row * DM_;
  int base = threadIdx.x * 8;
  f32x4 v0 = *(const f32x4*)(x + base);
  f32x4 v1 = *(const f32x4*)(x + base + 4);
  float xv[8], ss = 0.f;
  #pragma unroll
  for (int i = 0; i < 4; i++) { xv[i] = v0[i]; xv[4 + i] = v1[i]; }
  #pragma unroll
  for (int i = 0; i < 8; i++) ss += xv[i] * xv[i];
  ss = block_reduce_sum_256(ss);
  float r = rsqrtf(ss / (float)DM_ + EPS_);
  f32x4 w0 = *(const f32x4*)(w + base);
  f32x4 w1 = *(const f32x4*)(w + base + 4);
  bf16x8 o;
  #pragma unroll
  for (int i = 0; i < 4; i++) { o[i] = (bf16)(w0[i] * xv[i] * r); o[4 + i] = (bf16)(w1[i] * xv[4 + i] * r); }
  *(bf16x8*)(hs + (size_t)row * DM_ + base) = o;
}

// ---------------------------------------------------------------- weight f32->bf16
__global__ __launch_bounds__(256) void convert_w_kernel(
    const float* __restrict__ src, bf16* __restrict__ dst,
    long n_src, long n_dst) {
  long e = ((long)blockIdx.x * 256 + threadIdx.x) * 8;
  if (e >= n_dst) return;
  bf16x8 o;
  if (e < n_src) {
    f32x4 a = *(const f32x4*)(src + e);
    f32x4 b = *(const f32x4*)(src + e + 4);
    #pragma unroll
    for (int q = 0; q < 4; q++) { o[q] = (bf16)a[q]; o[4 + q] = (bf16)b[q]; }
  } else {
    #pragma unroll
    for (int q = 0; q < 8; q++) o[q] = (bf16)0.f;
  }
  *(bf16x8*)(dst + e) = o;
}

// ---------------------------------------------------------------- NT GEMM (m97 single-buffer + swizzle)
// C[M][N] = A[M][K].W[N][K]^T, bf16 in. 128x128 tile, BK=64, 4 waves (2x2),
// 32 KB LDS -> up to 5 blocks/CU (inter-block overlap absorbs the drain,
// m114/m97). XOR slot swizzle: LDS[row][s] = G[row][s^(row&7)] via
// pre-swizzled gload source; ds_read XORs the same key -> conflict-free.
// [round-8 verbatim: best measured GEMM for these shapes, 107 us]
template <bool OUT_F32>
__global__ __launch_bounds__(256, 4) void gemm_nt_sb(
    const bf16* __restrict__ A, int lda,
    const bf16* __restrict__ W, int ldw,
    void* __restrict__ Cout, int ldc, const float* __restrict__ resid,
    int N, int K) {
  __shared__ __align__(16) bf16 As[128 * 64];
  __shared__ __align__(16) bf16 Bs[128 * 64];
  // bijective XCD swizzle (m204)
  int nwg = gridDim.x * gridDim.y;
  int bid = blockIdx.y * gridDim.x + blockIdx.x;
  int q8 = nwg >> 3, r8 = nwg & 7;
  int xcd = bid & 7, loc = bid >> 3;
  int nb = (xcd < r8 ? xcd * (q8 + 1) : r8 * (q8 + 1) + (xcd - r8) * q8) + loc;
  int bn = nb % gridDim.x, bm = nb / gridDim.x;
  int m0 = bm * 128, n0 = bn * 128;
  int tid = threadIdx.x, wave = tid >> 6, lane = tid & 63;
  int wm = (wave >> 1) * 64, wn = (wave & 1) * 64;
  int lm = lane & 15, lk = (lane >> 4) * 8;
  int lr = lane >> 3;                  // row within 8-row chunk
  int cse = ((lane & 7) ^ lr) * 8;     // pre-swizzled source slot
  f32x4 acc[4][4] = {};

  int NT = K / 64;
  for (int t = 0; t < NT; ++t) {
    #pragma unroll
    for (int i = 0; i < 4; ++i) {
      int row = (wave * 4 + i) * 8;    // 16 chunks of 8 rows; 4 per wave
      async16(A + (size_t)(m0 + row + lr) * lda + t * 64 + cse, &As[row * 64]);
      async16(W + (size_t)(n0 + row + lr) * ldw + t * 64 + cse, &Bs[row * 64]);
    }
    WAITV(0);
    BAR();
    #pragma unroll
    for (int ks = 0; ks < 64; ks += 32) {
      bf16x8 af[4], bf[4];
      #pragma unroll
      for (int i = 0; i < 4; ++i) {
        int row = wm + i * 16 + lm;
        af[i] = *(const bf16x8*)&As[row * 64 + ((((ks + lk) >> 3) ^ (row & 7)) << 3)];
      }
      #pragma unroll
      for (int j = 0; j < 4; ++j) {
        int row = wn + j * 16 + lm;
        bf[j] = *(const bf16x8*)&Bs[row * 64 + ((((ks + lk) >> 3) ^ (row & 7)) << 3)];
      }
      #pragma unroll
      for (int i = 0; i < 4; ++i)
        #pragma unroll
        for (int j = 0; j < 4; ++j)
          acc[i][j] = __builtin_amdgcn_mfma_f32_16x16x32_bf16(af[i], bf[j], acc[i][j], 0, 0, 0);
    }
    BAR();
  }
  // ---- epilogue
  int r0 = m0 + wm + (lane >> 4) * 4;
  #pragma unroll
  for (int i = 0; i < 4; ++i) {
    #pragma unroll
    for (int j = 0; j < 4; ++j) {
      int col = n0 + wn + j * 16 + lm;
      if (col < N) {
        #pragma unroll
        for (int r = 0; r < 4; ++r) {
          int row = r0 + i * 16 + r;
          size_t idx = (size_t)row * ldc + col;
          float v = acc[i][j][r];
          if (resid) v += resid[idx];
          if (OUT_F32) ((float*)Cout)[idx] = v;
          else         ((bf16*)Cout)[idx]  = (bf16)v;
        }
      }
    }
  }
}

// ---------------------------------------------------------------- conv1d+SiLU (B/C cols only)
__global__ __launch_bounds__(256) void conv_bc_kernel(
    const bf16* __restrict__ xbcdt, const float* __restrict__ cw,
    const float* __restrict__ cb, bf16* __restrict__ xc) {
  int idx = blockIdx.x * 256 + threadIdx.x;
  if (idx >= BL_ * 16) return;          // 128 B/C cols / 8
  int c8 = idx & 15, t = idx >> 4;
  int l = t % L_;
  int c = DI_ + c8 * 8;
  float acc[8];
  f32x4 bv0 = *(const f32x4*)(cb + c);
  f32x4 bv1 = *(const f32x4*)(cb + c + 4);
  #pragma unroll
  for (int q = 0; q < 4; q++) { acc[q] = bv0[q]; acc[4 + q] = bv1[q]; }
  #pragma unroll
  for (int k = 0; k < 4; k++) {
    int ls = l + k - 3;
    if (ls >= 0) {
      const bf16* xp = xbcdt + (size_t)(t + k - 3) * XBCD_ + c;
      bf16x8 xv = *(const bf16x8*)xp;
      f32x4 wv0 = *(const f32x4*)(cw + k * CONV_ + c);
      f32x4 wv1 = *(const f32x4*)(cw + k * CONV_ + c + 4);
      #pragma unroll
      for (int q = 0; q < 4; q++) { acc[q] += (float)xv[q] * wv0[q]; acc[4 + q] += (float)xv[4 + q] * wv1[q]; }
    }
  }
  bf16x8 o;
  #pragma unroll
  for (int q = 0; q < 8; q++) o[q] = (bf16)silu_f(acc[q]);
  *(bf16x8*)(xc + (size_t)t * CONV_ + c) = o;
}

// ---------------------------------------------------------------- dt (softplus)
__global__ __launch_bounds__(256) void dt_kernel(
    const bf16* __restrict__ xbcdt, const float* __restrict__ dt_bias,
    float* __restrict__ dtH) {
  int idx = blockIdx.x * 256 + threadIdx.x;
  if (idx >= BL_ * NH) return;
  int h = idx & 63, t = idx >> 6;
  float raw = (float)xbcdt[(size_t)t * XBCD_ + CONV_ + h] + dt_bias[h];
  float v = (raw > 20.f) ? raw : log1pf(expf(raw));
  dtH[(size_t)h * BL_ + t] = v;
}

// ---------------------------------------------------------------- Atot precompute
__global__ __launch_bounds__(256) void atot_kernel(
    const float* __restrict__ dtH, const float* __restrict__ A_log,
    float* __restrict__ Atot) {
  int idx = blockIdx.x * 256 + threadIdx.x;
  if (idx >= B_ * NH * NCHUNK) return;
  int c = idx & 31, rem = idx >> 5;
  int h = rem & 63, b = rem >> 6;
  const float* p = dtH + (size_t)h * BL_ + b * L_ + c * 64;
  float s = 0.f;
  #pragma unroll 8
  for (int i = 0; i < 64; i++) s += p[i];
  Atot[idx] = expf(-expf(A_log[h]) * s);
}

// ---------------------------------------------------------------- scan pass 1 (MFMA SSD, fused x-conv)
__global__ __launch_bounds__(256) void scan_chunk_mfma(
    bf16* __restrict__ xc, const bf16* __restrict__ xbcdt,
    const float* __restrict__ cw, const float* __restrict__ cb,
    const float* __restrict__ dtH,
    const float* __restrict__ A_log, const float* __restrict__ Dp,
    bf16* __restrict__ Sc) {
  __shared__ bf16 Bs[64][72];   // B rows s, cols n   (swizzled)
  __shared__ bf16 Cs[64][72];   // C rows t, cols n   (natural)
  __shared__ bf16 Xt[64][72];   // x^T rows p, cols s (swizzled)
  __shared__ bf16 Gh[64][72];   // masked G hi  [t][s], later wB hi [n][s]
  __shared__ bf16 Gl[64][72];   // masked G lo  [t][s], later wB lo [n][s]
  __shared__ float dts[64];
  __shared__ float cum[64];
  __shared__ float wsA[64];
  int bi = blockIdx.x;
  int h = bi & 63, c = (bi >> 6) & 31, b = bi >> 11;
  int tid = threadIdx.x;
  int wave = tid >> 6, lane = tid & 63;
  int lm = lane & 15, lk = (lane >> 4) * 8;
  int cl = lane & 15, rw4 = (lane >> 4) * 4;
  int wt = (wave >> 1) * 32, wq = (wave & 1) * 32;
  size_t rowbase = (size_t)b * L_ + c * 64;
  float aA = expf(A_log[h]);
  // ---- stage: x via fused conv (registers), B (swizzled), C (natural)
  #pragma unroll
  for (int i = 0; i < 2; i++) {
    int cc = tid + i * 256;
    int s = cc >> 3, e8 = (cc & 7) * 8;
    const bf16* base = xc + (rowbase + s) * CONV_;
    bf16x8 bv = *(const bf16x8*)(base + DI_ + e8);
    bf16x8 cv = *(const bf16x8*)(base + DI_ + NST + e8);
    *(bf16x8*)&Bs[s][e8 ^ (s & 56)] = bv;
    *(bf16x8*)&Cs[s][e8] = cv;
    // fused depthwise conv + SiLU for x columns h*PD + e8 .. +7
    int col = h * PD + e8;
    int l = c * 64 + s;
    float acc[8];
    f32x4 cb0 = *(const f32x4*)(cb + col);
    f32x4 cb1 = *(const f32x4*)(cb + col + 4);
    #pragma unroll
    for (int q = 0; q < 4; q++) { acc[q] = cb0[q]; acc[4 + q] = cb1[q]; }
    #pragma unroll
    for (int k = 0; k < 4; k++) {
      int ls = l + k - 3;
      if (ls >= 0) {
        const bf16* xp = xbcdt + (rowbase + s + k - 3) * XBCD_ + col;
        bf16x8 xv = *(const bf16x8*)xp;
        f32x4 wv0 = *(const f32x4*)(cw + k * CONV_ + col);
        f32x4 wv1 = *(const f32x4*)(cw + k * CONV_ + col + 4);
        #pragma unroll
        for (int q = 0; q < 4; q++) { acc[q] += (float)xv[q] * wv0[q]; acc[4 + q] += (float)xv[4 + q] * wv1[q]; }
      }
    }
    #pragma unroll
    for (int q = 0; q < 8; q++) Xt[e8 + q][s ^ e8] = (bf16)silu_f(acc[q]);
  }
  if (tid < 64) dts[tid] = dtH[(size_t)h * BL_ + rowbase + tid];
  __syncthreads();
  // ---- inclusive prefix sum of dt (wave 0)
  if (tid < 64) {
    float v = dts[tid];
    #pragma unroll
    for (int off = 1; off < 64; off <<= 1) {
      float o = __shfl_up(v, off, 64);
      if (tid >= off) v += o;
    }
    cum[tid] = v;
  }
  __syncthreads();
  if (tid < 64) wsA[tid] = expf(-aA * (cum[63] - cum[tid])) * dts[tid];
  // ---- G[t][s] = sum_n C[t][n] * B[s][n]
  f32x4 gacc[2][2] = {};
  #pragma unroll
  for (int ks = 0; ks < 64; ks += 32) {
    bf16x8 af[2], bfr[2];
    #pragma unroll
    for (int i = 0; i < 2; i++) af[i] = *(bf16x8*)&Cs[wt + i * 16 + lm][ks + lk];
    #pragma unroll
    for (int j = 0; j < 2; j++) {
      int S = wq + j * 16 + lm;
      bfr[j] = *(bf16x8*)&Bs[S][(ks + lk) ^ (S & 56)];
    }
    #pragma unroll
    for (int i = 0; i < 2; i++)
      #pragma unroll
      for (int j = 0; j < 2; j++)
        gacc[i][j] = __builtin_amdgcn_mfma_f32_16x16x32_bf16(af[i], bfr[j], gacc[i][j], 0, 0, 0);
  }
  // ---- causal decay mask, hi/lo split -> Gh/Gl [t][s]
  #pragma unroll
  for (int i = 0; i < 2; i++) {
    #pragma unroll
    for (int j = 0; j < 2; j++) {
      #pragma unroll
      for (int r = 0; r < 4; r++) {
        int t = wt + i * 16 + rw4 + r;
        int s = wq + j * 16 + cl;
        float g = 0.f;
        if (s <= t) g = gacc[i][j][r] * expf(-aA * (cum[t] - cum[s])) * dts[s];
        bf16 ghi = (bf16)g;
        Gh[t][s] = ghi;
        Gl[t][s] = (bf16)(g - (float)ghi);
      }
    }
  }
  __syncthreads();
  // ---- Y[t][p] = sum_s Gm[t][s] * x_s[p];  + D*x; write into xc x-region
  f32x4 yacc[2][2] = {};
  #pragma unroll
  for (int ks = 0; ks < 64; ks += 32) {
    bf16x8 ah[2], al[2], bx[2];
    #pragma unroll
    for (int i = 0; i < 2; i++) {
      ah[i] = *(bf16x8*)&Gh[wt + i * 16 + lm][ks + lk];
      al[i] = *(bf16x8*)&Gl[wt + i * 16 + lm][ks + lk];
    }
    #pragma unroll
    for (int j = 0; j < 2; j++) {
      int P = wq + j * 16 + lm;
      bx[j] = *(bf16x8*)&Xt[P][(ks + lk) ^ (P & 56)];
    }
    #pragma unroll
    for (int i = 0; i < 2; i++)
      #pragma unroll
      for (int j = 0; j < 2; j++) {
        yacc[i][j] = __builtin_amdgcn_mfma_f32_16x16x32_bf16(ah[i], bx[j], yacc[i][j], 0, 0, 0);
        yacc[i][j] = __builtin_amdgcn_mfma_f32_16x16x32_bf16(al[i], bx[j], yacc[i][j], 0, 0, 0);
      }
  }
  float Dv = Dp[h];
  #pragma unroll
  for (int i = 0; i < 2; i++) {
    #pragma unroll
    for (int j = 0; j < 2; j++) {
      int p = wq + j * 16 + cl;
      #pragma unroll
      for (int r = 0; r < 4; r++) {
        int t = wt + i * 16 + rw4 + r;
        float yv = yacc[i][j][r] + Dv * (float)Xt[p][t ^ (p & 56)];
        xc[(rowbase + t) * CONV_ + h * PD + p] = (bf16)yv;
      }
    }
  }
  __syncthreads();
  // ---- wB[n][s] = w_s * B_s[n], hi/lo into Gh/Gl (reuse buffers)
  #pragma unroll
  for (int i = 0; i < 2; i++) {
    int cc = tid + i * 256;
    int n = cc >> 3, s8 = (cc & 7) * 8;
    bf16x8 vh, vl;
    #pragma unroll
    for (int q = 0; q < 8; q++) {
      int s = s8 + q;
      float wb = (float)Bs[s][n ^ (s & 56)] * wsA[s];
      vh[q] = (bf16)wb;
      vl[q] = (bf16)(wb - (float)vh[q]);
    }
    *(bf16x8*)&Gh[n][s8] = vh;
    *(bf16x8*)&Gl[n][s8] = vl;
  }
  __syncthreads();
  // ---- S[p][n] = sum_s x_s[p] * wB[n][s]; write Sc
  f32x4 sacc[2][2] = {};
  #pragma unroll
  for (int ks = 0; ks < 64; ks += 32) {
    bf16x8 ax[2], bh[2], bl[2];
    #pragma unroll
    for (int i = 0; i < 2; i++) {
      int P = wt + i * 16 + lm;
      ax[i] = *(bf16x8*)&Xt[P][(ks + lk) ^ (P & 56)];
    }
    #pragma unroll
    for (int j = 0; j < 2; j++) {
      bh[j] = *(bf16x8*)&Gh[wq + j * 16 + lm][ks + lk];
      bl[j] = *(bf16x8*)&Gl[wq + j * 16 + lm][ks + lk];
    }
    #pragma unroll
    for (int i = 0; i < 2; i++)
      #pragma unroll
      for (int j = 0; j < 2; j++) {
        sacc[i][j] = __builtin_amdgcn_mfma_f32_16x16x32_bf16(ax[i], bh[j], sacc[i][j], 0, 0, 0);
        sacc[i][j] = __builtin_amdgcn_mfma_f32_16x16x32_bf16(ax[i], bl[j], sacc[i][j], 0, 0, 0);
      }
  }
  bf16* scp = Sc + ((((size_t)b * NCHUNK + c) * NH + h) << 12);
  #pragma unroll
  for (int i = 0; i < 2; i++) {
    #pragma unroll
    for (int j = 0; j < 2; j++) {
      int n = wq + j * 16 + cl;
      #pragma unroll
      for (int r = 0; r < 4; r++) {
        int p = wt + i * 16 + rw4 + r;
        scp[p * 64 + n] = (bf16)sacc[i][j][r];
      }
    }
  }
}

// ---------------------------------------------------------------- scan pass 2 (element-parallel, bf16x8)
// 256 blocks; each thread owns 8 CONTIGUOUS (p,n) elements of one (b,h) and
// walks the 32 chunks serially: o_c = H; H = Atot[c]*H + S_c. Fully
// coalesced 16B/lane (was 2B/lane scalar). Same math/order as before.
__global__ __launch_bounds__(256) void state_scan_kernel(
    bf16* __restrict__ Sc, const float* __restrict__ Atot) {
  __shared__ float At[NCHUNK];
  int bid = blockIdx.x;
  int seg = bid & 1, rem = bid >> 1;           // rem = b*64 + h
  if (threadIdx.x < NCHUNK) At[threadIdx.x] = Atot[(rem << 5) + threadIdx.x];
  __syncthreads();
  int h = rem & 63, b = rem >> 6;
  int e = seg * 2048 + threadIdx.x * 8;        // element base in [0,4096)
  bf16* p = Sc + ((((size_t)b * NCHUNK) * NH + h) << 12) + e;
  const size_t cstride = (size_t)NH << 12;
  float H[8] = {};
  for (int c = 0; c < NCHUNK; ++c) {
    bf16x8 s = *(bf16x8*)p;
    bf16x8 o;
    #pragma unroll
    for (int q = 0; q < 8; ++q) {
      o[q] = (bf16)H[q];                       // h_prev for chunk c
      H[q] = At[c] * H[q] + (float)s[q];
    }
    *(bf16x8*)p = o;
    p += cstride;
  }
}

// ---------------------------------------------------------------- scan pass 3 (MFMA)
__global__ __launch_bounds__(256) void y_inter_mfma(
    bf16* __restrict__ xc, const float* __restrict__ dtH,
    const float* __restrict__ A_log, const bf16* __restrict__ Sc) {
  __shared__ bf16 Cs[64][72];
  __shared__ bf16 Hs[64][72];
  __shared__ float dts[64];
  __shared__ float eA[64];
  int bi = blockIdx.x;
  int h = bi & 63, c = (bi >> 6) & 31, b = bi >> 11;
  int tid = threadIdx.x;
  int wave = tid >> 6, lane = tid & 63;
  int lm = lane & 15, lk = (lane >> 4) * 8;
  int cl = lane & 15, rw4 = (lane >> 4) * 4;
  int wt = (wave >> 1) * 32, wp = (wave & 1) * 32;
  size_t rowbase = (size_t)b * L_ + c * 64;
  float aA = expf(A_log[h]);
  const bf16* scp = Sc + ((((size_t)b * NCHUNK + c) * NH + h) << 12);
  #pragma unroll
  for (int i = 0; i < 2; i++) {
    int cc = tid + i * 256;
    int s = cc >> 3, e8 = (cc & 7) * 8;
    bf16x8 cv = *(const bf16x8*)(xc + (rowbase + s) * CONV_ + DI_ + NST + e8);
    *(bf16x8*)&Cs[s][e8] = cv;
  }
  {
    int p = tid >> 2, n16 = (tid & 3) * 16;
    *(bf16x8*)&Hs[p][n16]     = *(const bf16x8*)(scp + p * 64 + n16);
    *(bf16x8*)&Hs[p][n16 + 8] = *(const bf16x8*)(scp + p * 64 + n16 + 8);
  }
  if (tid < 64) dts[tid] = dtH[(size_t)h * BL_ + rowbase + tid];
  __syncthreads();
  if (tid < 64) {
    float v = dts[tid];
    #pragma unroll
    for (int off = 1; off < 64; off <<= 1) {
      float o = __shfl_up(v, off, 64);
      if (tid >= off) v += o;
    }
    eA[tid] = expf(-aA * v);
  }
  __syncthreads();
  f32x4 acc[2][2] = {};
  #pragma unroll
  for (int ks = 0; ks < 64; ks += 32) {
    bf16x8 af[2], bfr[2];
    #pragma unroll
    for (int i = 0; i < 2; i++) af[i]  = *(bf16x8*)&Cs[wt + i * 16 + lm][ks + lk];
    #pragma unroll
    for (int j = 0; j < 2; j++) bfr[j] = *(bf16x8*)&Hs[wp + j * 16 + lm][ks + lk];
    #pragma unroll
    for (int i = 0; i < 2; i++)
      #pragma unroll
      for (int j = 0; j < 2; j++)
        acc[i][j] = __builtin_amdgcn_mfma_f32_16x16x32_bf16(af[i], bfr[j], acc[i][j], 0, 0, 0);
  }
  #pragma unroll
  for (int i = 0; i < 2; i++) {
    #pragma unroll
    for (int j = 0; j < 2; j++) {
      int p = wp + j * 16 + cl;
      #pragma unroll
      for (int r = 0; r < 4; r++) {
        int t = wt + i * 16 + rw4 + r;
        size_t gi = (rowbase + t) * CONV_ + h * PD + p;
        xc[gi] = (bf16)((float)xc[gi] + eA[t] * acc[i][j][r]);
      }
    }
  }
}

// ---------------------------------------------------------------- gated RMSNorm
__global__ __launch_bounds__(256) void gated_norm_kernel(
    const bf16* __restrict__ xc, bf16* __restrict__ zbuf,
    const float* __restrict__ nw) {
  int t = blockIdx.x;
  int base = threadIdx.x * 16;
  const bf16* yr = xc + (size_t)t * CONV_;
  bf16* zr = zbuf + (size_t)t * DI_;
  float tv[16], ss = 0.f;
  #pragma unroll
  for (int i8 = 0; i8 < 2; i8++) {
    bf16x8 yv = *(const bf16x8*)(yr + base + i8 * 8);
    bf16x8 zv = *(const bf16x8*)(zr + base + i8 * 8);
    #pragma unroll
    for (int q = 0; q < 8; q++) {
      float tt = (float)yv[q] * silu_f((float)zv[q]);
      tv[i8 * 8 + q] = tt;
      ss += tt * tt;
    }
  }
  ss = block_reduce_sum_256(ss);
  float r = rsqrtf(ss / (float)DI_ + EPS_);
  #pragma unroll
  for (int i8 = 0; i8 < 2; i8++) {
    f32x4 w0 = *(const f32x4*)(nw + base + i8 * 8);
    f32x4 w1 = *(const f32x4*)(nw + base + i8 * 8 + 4);
    bf16x8 o;
    #pragma unroll
    for (int q = 0; q < 4; q++) {
      o[q]     = (bf16)(w0[q] * tv[i8 * 8 + q] * r);
      o[4 + q] = (bf16)(w1[q] * tv[i8 * 8 + 4 + q] * r);
    }
    *(bf16x8*)(zr + base + i8 * 8) = o;
  }
}

// ---------------------------------------------------------------- ws diagnostic
__global__ void ws_report_kernel(float* out, float ws_mb) {
  if (blockIdx.x == 0 && threadIdx.x == 0) out[0] = ws_mb;
}

// ---------------------------------------------------------------- launch
extern "C" void kernel_launch(void* const* d_in, const int* in_sizes, int n_in,
                              void* d_out, int out_size, void* d_ws, size_t ws_size,
                              hipStream_t stream) {
  const float* u        = (const float*)d_in[0];
  const float* ln_w     = (const float*)d_in[1];
  const float* in_proj  = (const float*)d_in[2];
  const float* conv_w   = (const float*)d_in[3];
  const float* conv_b   = (const float*)d_in[4];
  const float* dt_bias  = (const float*)d_in[5];
  const float* A_log    = (const float*)d_in[6];
  const float* Dp       = (const float*)d_in[7];
  const float* norm_w   = (const float*)d_in[8];
  const float* out_proj = (const float*)d_in[9];
  float* out = (float*)d_out;

  bf16* hs = (bf16*)d_out;     // scratch inside d_out (dead before final GEMM)

  char* ws = (char*)d_ws;
  size_t off = 0;
  auto alloc = [&](size_t bytes) { char* p = ws + off; off = (off + bytes + 255) & ~(size_t)255; return p; };
  float* dtH  = (float*)alloc((size_t)BL_ * NH * 4);          //  1.05 MB  [h][b*L+t]
  float* Atot = (float*)alloc((size_t)B_ * NH * NCHUNK * 4);  //  16 KB
  bf16*  wbuf = (bf16*)alloc((size_t)4352 * DM_ * 2);         // 17.8 MB bf16 weight slice
  bf16*  shbuf= (bf16*)alloc((size_t)BL_ * XBCD_ * 2);        // 35.1 MB (xbcdt → zbuf)
  bf16*  xc   = (bf16*)alloc((size_t)BL_ * CONV_ * 2);        // 34.6 MB
  bf16*  Sc   = (bf16*)alloc((size_t)B_ * NCHUNK * NH * 64 * 64 * 2);  // 32 MB
  size_t need = off;                                          // ~120.6 MB

  if (ws_size < need) {
    ws_report_kernel<<<1, 64, 0, stream>>>(out, (float)(ws_size >> 20));
    return;
  }

  bf16* xbcdt = shbuf;          // phase 1: BL x XBCD_  (live through scan pass 1)
  bf16* zbuf  = shbuf;          // phase 3: BL x DI_

  rmsnorm_in_kernel<<<BL_, 256, 0, stream>>>(u, ln_w, hs);

  // GEMM1: zxbcdt tail (xBC + dt), weights padded to 4352 rows.
  {
    long nsrc = (long)XBCD_ * DM_, ndst = (long)4352 * DM_;
    convert_w_kernel<<<(int)(ndst / 8 / 256), 256, 0, stream>>>(
        in_proj + (size_t)DI_ * DM_, wbuf, nsrc, ndst);
    gemm_nt_sb<false><<<dim3(4352 / 128, BL_ / 128), 256, 0, stream>>>(
        hs, DM_, wbuf, DM_, xbcdt, XBCD_, nullptr, XBCD_, DM_);
  }
  conv_bc_kernel<<<(BL_ * 16 + 255) / 256, 256, 0, stream>>>(
      xbcdt, conv_w, conv_b, xc);
  dt_kernel<<<(BL_ * NH + 255) / 256, 256, 0, stream>>>(
      xbcdt, dt_bias, dtH);
  atot_kernel<<<(B_ * NH * NCHUNK + 255) / 256, 256, 0, stream>>>(
      dtH, A_log, Atot);
  // chunked SSD scan with fused x-conv (xbcdt still live)
  scan_chunk_mfma<<<B_ * NH * NCHUNK, 256, 0, stream>>>(
      xc, xbcdt, conv_w, conv_b, dtH, A_log, Dp, Sc);
  state_scan_kernel<<<B_ * NH * 2, 256, 0, stream>>>(Sc, Atot);
  y_inter_mfma<<<B_ * NH * NCHUNK, 256, 0, stream>>>(xc, dtH, A_log, Sc);

  // GEMM2: z part of in_proj (xbcdt dead; shbuf becomes zbuf)
  {
    long n = (long)DI_ * DM_;
    convert_w_kernel<<<(int)(n / 8 / 256), 256, 0, stream>>>(in_proj, wbuf, n, n);
    gemm_nt_sb<false><<<dim3(DI_ / 128, BL_ / 128), 256, 0, stream>>>(
        hs, DM_, wbuf, DM_, zbuf, DI_, nullptr, DI_, DM_);
  }
  gated_norm_kernel<<<BL_, 256, 0, stream>>>(xc, zbuf, norm_w);

  // GEMM3: out projection + residual
  {
    long n = (long)DM_ * DI_;
    convert_w_kernel<<<(int)(n / 8 / 256), 256, 0, stream>>>(out_proj, wbuf, n, n);
    gemm_nt_sb<true><<<dim3(DM_ / 128, BL_ / 128), 256, 0, stream>>>(
        zbuf, DI_, wbuf, DI_, out, DM_, u, DM_, DI_);
  }
}

// Round 13
// 558.605 us; speedup vs baseline: 2.1828x; 1.0273x over previous
//
#include <hip/hip_runtime.h>
#include <hip/hip_bf16.h>

typedef __bf16 bf16;
typedef __bf16 bf16x8 __attribute__((ext_vector_type(8)));
typedef float f32x4 __attribute__((ext_vector_type(4)));

#define B_    2
#define L_    2048
#define DM_   2048
#define DI_   4096
#define NST   64
#define PD    64
#define NH    64
#define CONV_ 4224
#define XBCD_ 4288            // CONV_ + NH  (xBC + dt columns)
#define PROJ_ 8384
#define BL_   (B_ * L_)
#define NCHUNK 32             // L_ / 64
#define EPS_  1e-6f

#define WAITV(n) asm volatile("s_waitcnt vmcnt(" #n ")" ::: "memory")
#define BAR()    __builtin_amdgcn_s_barrier()

// ---------------------------------------------------------------- reductions
__device__ __forceinline__ float block_reduce_sum_256(float v) {
  #pragma unroll
  for (int m = 32; m; m >>= 1) v += __shfl_xor(v, m, 64);
  __shared__ float sred[4];
  int w = threadIdx.x >> 6;
  if ((threadIdx.x & 63) == 0) sred[w] = v;
  __syncthreads();
  return sred[0] + sred[1] + sred[2] + sred[3];
}

__device__ __forceinline__ float silu_f(float x) {
  return x / (1.0f + expf(-x));
}

// async global->LDS, 16B per lane. LDS dest is wave-uniform base; HW adds
// lane*16. [m97/m104 semantics]
__device__ __forceinline__ void async16(const bf16* g, bf16* l) {
  __builtin_amdgcn_global_load_lds(
      (__attribute__((address_space(1))) void*)g,
      (__attribute__((address_space(3))) void*)l, 16, 0, 0);
}

// ---------------------------------------------------------------- RMSNorm in
__global__ __launch_bounds__(256) void rmsnorm_in_kernel(
    const float* __restrict__ u, const float* __restrict__ w, bf16* __restrict__ hs) {
  int row = blockIdx.x;
  const float* x = u + (size_t)row * DM_;
  int base = threadIdx.x * 8;
  f32x4 v0 = *(const f32x4*)(x + base);
  f32x4 v1 = *(const f32x4*)(x + base + 4);
  float xv[8], ss = 0.f;
  #pragma unroll
  for (int i = 0; i < 4; i++) { xv[i] = v0[i]; xv[4 + i] = v1[i]; }
  #pragma unroll
  for (int i = 0; i < 8; i++) ss += xv[i] * xv[i];
  ss = block_reduce_sum_256(ss);
  float r = rsqrtf(ss / (float)DM_ + EPS_);
  f32x4 w0 = *(const f32x4*)(w + base);
  f32x4 w1 = *(const f32x4*)(w + base + 4);
  bf16x8 o;
  #pragma unroll
  for (int i = 0; i < 4; i++) { o[i] = (bf16)(w0[i] * xv[i] * r); o[4 + i] = (bf16)(w1[i] * xv[4 + i] * r); }
  *(bf16x8*)(hs + (size_t)row * DM_ + base) = o;
}

// ---------------------------------------------------------------- weight f32->bf16
__global__ __launch_bounds__(256) void convert_w_kernel(
    const float* __restrict__ src, bf16* __restrict__ dst,
    long n_src, long n_dst) {
  long e = ((long)blockIdx.x * 256 + threadIdx.x) * 8;
  if (e >= n_dst) return;
  bf16x8 o;
  if (e < n_src) {
    f32x4 a = *(const f32x4*)(src + e);
    f32x4 b = *(const f32x4*)(src + e + 4);
    #pragma unroll
    for (int q = 0; q < 4; q++) { o[q] = (bf16)a[q]; o[4 + q] = (bf16)b[q]; }
  } else {
    #pragma unroll
    for (int q = 0; q < 8; q++) o[q] = (bf16)0.f;
  }
  *(bf16x8*)(dst + e) = o;
}

// ---------------------------------------------------------------- NT GEMM (m97 single-buffer + swizzle)
// C[M][N] = A[M][K].W[N][K]^T, bf16 in. 128x128 tile, BK=64, 4 waves (2x2),
// 32 KB LDS -> up to 5 blocks/CU (inter-block overlap absorbs the drain,
// m114/m97). XOR slot swizzle: LDS[row][s] = G[row][s^(row&7)] via
// pre-swizzled gload source; ds_read XORs the same key -> conflict-free.
// [round-8 verbatim: best measured GEMM for these shapes, ~107 us]
template <bool OUT_F32>
__global__ __launch_bounds__(256, 4) void gemm_nt_sb(
    const bf16* __restrict__ A, int lda,
    const bf16* __restrict__ W, int ldw,
    void* __restrict__ Cout, int ldc, const float* __restrict__ resid,
    int N, int K) {
  __shared__ __align__(16) bf16 As[128 * 64];
  __shared__ __align__(16) bf16 Bs[128 * 64];
  // bijective XCD swizzle (m204)
  int nwg = gridDim.x * gridDim.y;
  int bid = blockIdx.y * gridDim.x + blockIdx.x;
  int q8 = nwg >> 3, r8 = nwg & 7;
  int xcd = bid & 7, loc = bid >> 3;
  int nb = (xcd < r8 ? xcd * (q8 + 1) : r8 * (q8 + 1) + (xcd - r8) * q8) + loc;
  int bn = nb % gridDim.x, bm = nb / gridDim.x;
  int m0 = bm * 128, n0 = bn * 128;
  int tid = threadIdx.x, wave = tid >> 6, lane = tid & 63;
  int wm = (wave >> 1) * 64, wn = (wave & 1) * 64;
  int lm = lane & 15, lk = (lane >> 4) * 8;
  int lr = lane >> 3;                  // row within 8-row chunk
  int cse = ((lane & 7) ^ lr) * 8;     // pre-swizzled source slot
  f32x4 acc[4][4] = {};

  int NT = K / 64;
  for (int t = 0; t < NT; ++t) {
    #pragma unroll
    for (int i = 0; i < 4; ++i) {
      int row = (wave * 4 + i) * 8;    // 16 chunks of 8 rows; 4 per wave
      async16(A + (size_t)(m0 + row + lr) * lda + t * 64 + cse, &As[row * 64]);
      async16(W + (size_t)(n0 + row + lr) * ldw + t * 64 + cse, &Bs[row * 64]);
    }
    WAITV(0);
    BAR();
    #pragma unroll
    for (int ks = 0; ks < 64; ks += 32) {
      bf16x8 af[4], bf[4];
      #pragma unroll
      for (int i = 0; i < 4; ++i) {
        int row = wm + i * 16 + lm;
        af[i] = *(const bf16x8*)&As[row * 64 + ((((ks + lk) >> 3) ^ (row & 7)) << 3)];
      }
      #pragma unroll
      for (int j = 0; j < 4; ++j) {
        int row = wn + j * 16 + lm;
        bf[j] = *(const bf16x8*)&Bs[row * 64 + ((((ks + lk) >> 3) ^ (row & 7)) << 3)];
      }
      #pragma unroll
      for (int i = 0; i < 4; ++i)
        #pragma unroll
        for (int j = 0; j < 4; ++j)
          acc[i][j] = __builtin_amdgcn_mfma_f32_16x16x32_bf16(af[i], bf[j], acc[i][j], 0, 0, 0);
    }
    BAR();
  }
  // ---- epilogue
  int r0 = m0 + wm + (lane >> 4) * 4;
  #pragma unroll
  for (int i = 0; i < 4; ++i) {
    #pragma unroll
    for (int j = 0; j < 4; ++j) {
      int col = n0 + wn + j * 16 + lm;
      if (col < N) {
        #pragma unroll
        for (int r = 0; r < 4; ++r) {
          int row = r0 + i * 16 + r;
          size_t idx = (size_t)row * ldc + col;
          float v = acc[i][j][r];
          if (resid) v += resid[idx];
          if (OUT_F32) ((float*)Cout)[idx] = v;
          else         ((bf16*)Cout)[idx]  = (bf16)v;
        }
      }
    }
  }
}

// ---------------------------------------------------------------- conv(B/C) + dt (merged)
// First BL_*16 tids: depthwise conv+SiLU over the 128 B/C cols.
// Remaining BL_*64 tids: softplus dt -> dtH[h][b*L+t].
__global__ __launch_bounds__(256) void convdt_kernel(
    const bf16* __restrict__ xbcdt, const float* __restrict__ cw,
    const float* __restrict__ cb, bf16* __restrict__ xc,
    const float* __restrict__ dt_bias, float* __restrict__ dtH) {
  int idx = blockIdx.x * 256 + threadIdx.x;
  if (idx < BL_ * 16) {
    int c8 = idx & 15, t = idx >> 4;
    int l = t % L_;
    int c = DI_ + c8 * 8;
    float acc[8];
    f32x4 bv0 = *(const f32x4*)(cb + c);
    f32x4 bv1 = *(const f32x4*)(cb + c + 4);
    #pragma unroll
    for (int q = 0; q < 4; q++) { acc[q] = bv0[q]; acc[4 + q] = bv1[q]; }
    #pragma unroll
    for (int k = 0; k < 4; k++) {
      int ls = l + k - 3;
      if (ls >= 0) {
        const bf16* xp = xbcdt + (size_t)(t + k - 3) * XBCD_ + c;
        bf16x8 xv = *(const bf16x8*)xp;
        f32x4 wv0 = *(const f32x4*)(cw + k * CONV_ + c);
        f32x4 wv1 = *(const f32x4*)(cw + k * CONV_ + c + 4);
        #pragma unroll
        for (int q = 0; q < 4; q++) { acc[q] += (float)xv[q] * wv0[q]; acc[4 + q] += (float)xv[4 + q] * wv1[q]; }
      }
    }
    bf16x8 o;
    #pragma unroll
    for (int q = 0; q < 8; q++) o[q] = (bf16)silu_f(acc[q]);
    *(bf16x8*)(xc + (size_t)t * CONV_ + c) = o;
  } else {
    int e = idx - BL_ * 16;
    if (e >= BL_ * NH) return;
    int h = e & 63, t = e >> 6;
    float raw = (float)xbcdt[(size_t)t * XBCD_ + CONV_ + h] + dt_bias[h];
    float v = (raw > 20.f) ? raw : log1pf(expf(raw));
    dtH[(size_t)h * BL_ + t] = v;
  }
}

// ---------------------------------------------------------------- Atot precompute
__global__ __launch_bounds__(256) void atot_kernel(
    const float* __restrict__ dtH, const float* __restrict__ A_log,
    float* __restrict__ Atot) {
  int idx = blockIdx.x * 256 + threadIdx.x;
  if (idx >= B_ * NH * NCHUNK) return;
  int c = idx & 31, rem = idx >> 5;
  int h = rem & 63, b = rem >> 6;
  const float* p = dtH + (size_t)h * BL_ + b * L_ + c * 64;
  float s = 0.f;
  #pragma unroll 8
  for (int i = 0; i < 64; i++) s += p[i];
  Atot[idx] = expf(-expf(A_log[h]) * s);
}

// ---------------------------------------------------------------- scan pass 1 (MFMA SSD, fused x-conv)
__global__ __launch_bounds__(256) void scan_chunk_mfma(
    bf16* __restrict__ xc, const bf16* __restrict__ xbcdt,
    const float* __restrict__ cw, const float* __restrict__ cb,
    const float* __restrict__ dtH,
    const float* __restrict__ A_log, const float* __restrict__ Dp,
    bf16* __restrict__ Sc) {
  __shared__ bf16 Bs[64][72];   // B rows s, cols n   (swizzled)
  __shared__ bf16 Cs[64][72];   // C rows t, cols n   (natural)
  __shared__ bf16 Xt[64][72];   // x^T rows p, cols s (swizzled)
  __shared__ bf16 Gh[64][72];   // masked G hi  [t][s], later wB hi [n][s]
  __shared__ bf16 Gl[64][72];   // masked G lo  [t][s], later wB lo [n][s]
  __shared__ float dts[64];
  __shared__ float cum[64];
  __shared__ float wsA[64];
  int bi = blockIdx.x;
  int h = bi & 63, c = (bi >> 6) & 31, b = bi >> 11;
  int tid = threadIdx.x;
  int wave = tid >> 6, lane = tid & 63;
  int lm = lane & 15, lk = (lane >> 4) * 8;
  int cl = lane & 15, rw4 = (lane >> 4) * 4;
  int wt = (wave >> 1) * 32, wq = (wave & 1) * 32;
  size_t rowbase = (size_t)b * L_ + c * 64;
  float aA = expf(A_log[h]);
  // ---- stage: x via fused conv (registers), B (swizzled), C (natural)
  #pragma unroll
  for (int i = 0; i < 2; i++) {
    int cc = tid + i * 256;
    int s = cc >> 3, e8 = (cc & 7) * 8;
    const bf16* base = xc + (rowbase + s) * CONV_;
    bf16x8 bv = *(const bf16x8*)(base + DI_ + e8);
    bf16x8 cv = *(const bf16x8*)(base + DI_ + NST + e8);
    *(bf16x8*)&Bs[s][e8 ^ (s & 56)] = bv;
    *(bf16x8*)&Cs[s][e8] = cv;
    // fused depthwise conv + SiLU for x columns h*PD + e8 .. +7
    int col = h * PD + e8;
    int l = c * 64 + s;
    float acc[8];
    f32x4 cb0 = *(const f32x4*)(cb + col);
    f32x4 cb1 = *(const f32x4*)(cb + col + 4);
    #pragma unroll
    for (int q = 0; q < 4; q++) { acc[q] = cb0[q]; acc[4 + q] = cb1[q]; }
    #pragma unroll
    for (int k = 0; k < 4; k++) {
      int ls = l + k - 3;
      if (ls >= 0) {
        const bf16* xp = xbcdt + (rowbase + s + k - 3) * XBCD_ + col;
        bf16x8 xv = *(const bf16x8*)xp;
        f32x4 wv0 = *(const f32x4*)(cw + k * CONV_ + col);
        f32x4 wv1 = *(const f32x4*)(cw + k * CONV_ + col + 4);
        #pragma unroll
        for (int q = 0; q < 4; q++) { acc[q] += (float)xv[q] * wv0[q]; acc[4 + q] += (float)xv[4 + q] * wv1[q]; }
      }
    }
    #pragma unroll
    for (int q = 0; q < 8; q++) Xt[e8 + q][s ^ e8] = (bf16)silu_f(acc[q]);
  }
  if (tid < 64) dts[tid] = dtH[(size_t)h * BL_ + rowbase + tid];
  __syncthreads();
  // ---- inclusive prefix sum of dt (wave 0)
  if (tid < 64) {
    float v = dts[tid];
    #pragma unroll
    for (int off = 1; off < 64; off <<= 1) {
      float o = __shfl_up(v, off, 64);
      if (tid >= off) v += o;
    }
    cum[tid] = v;
  }
  __syncthreads();
  if (tid < 64) wsA[tid] = expf(-aA * (cum[63] - cum[tid])) * dts[tid];
  // ---- G[t][s] = sum_n C[t][n] * B[s][n]
  f32x4 gacc[2][2] = {};
  #pragma unroll
  for (int ks = 0; ks < 64; ks += 32) {
    bf16x8 af[2], bfr[2];
    #pragma unroll
    for (int i = 0; i < 2; i++) af[i] = *(bf16x8*)&Cs[wt + i * 16 + lm][ks + lk];
    #pragma unroll
    for (int j = 0; j < 2; j++) {
      int S = wq + j * 16 + lm;
      bfr[j] = *(bf16x8*)&Bs[S][(ks + lk) ^ (S & 56)];
    }
    #pragma unroll
    for (int i = 0; i < 2; i++)
      #pragma unroll
      for (int j = 0; j < 2; j++)
        gacc[i][j] = __builtin_amdgcn_mfma_f32_16x16x32_bf16(af[i], bfr[j], gacc[i][j], 0, 0, 0);
  }
  // ---- causal decay mask, hi/lo split -> Gh/Gl [t][s]
  #pragma unroll
  for (int i = 0; i < 2; i++) {
    #pragma unroll
    for (int j = 0; j < 2; j++) {
      #pragma unroll
      for (int r = 0; r < 4; r++) {
        int t = wt + i * 16 + rw4 + r;
        int s = wq + j * 16 + cl;
        float g = 0.f;
        if (s <= t) g = gacc[i][j][r] * expf(-aA * (cum[t] - cum[s])) * dts[s];
        bf16 ghi = (bf16)g;
        Gh[t][s] = ghi;
        Gl[t][s] = (bf16)(g - (float)ghi);
      }
    }
  }
  __syncthreads();
  // ---- Y[t][p] = sum_s Gm[t][s] * x_s[p];  + D*x; write into xc x-region
  f32x4 yacc[2][2] = {};
  #pragma unroll
  for (int ks = 0; ks < 64; ks += 32) {
    bf16x8 ah[2], al[2], bx[2];
    #pragma unroll
    for (int i = 0; i < 2; i++) {
      ah[i] = *(bf16x8*)&Gh[wt + i * 16 + lm][ks + lk];
      al[i] = *(bf16x8*)&Gl[wt + i * 16 + lm][ks + lk];
    }
    #pragma unroll
    for (int j = 0; j < 2; j++) {
      int P = wq + j * 16 + lm;
      bx[j] = *(bf16x8*)&Xt[P][(ks + lk) ^ (P & 56)];
    }
    #pragma unroll
    for (int i = 0; i < 2; i++)
      #pragma unroll
      for (int j = 0; j < 2; j++) {
        yacc[i][j] = __builtin_amdgcn_mfma_f32_16x16x32_bf16(ah[i], bx[j], yacc[i][j], 0, 0, 0);
        yacc[i][j] = __builtin_amdgcn_mfma_f32_16x16x32_bf16(al[i], bx[j], yacc[i][j], 0, 0, 0);
      }
  }
  float Dv = Dp[h];
  #pragma unroll
  for (int i = 0; i < 2; i++) {
    #pragma unroll
    for (int j = 0; j < 2; j++) {
      int p = wq + j * 16 + cl;
      #pragma unroll
      for (int r = 0; r < 4; r++) {
        int t = wt + i * 16 + rw4 + r;
        float yv = yacc[i][j][r] + Dv * (float)Xt[p][t ^ (p & 56)];
        xc[(rowbase + t) * CONV_ + h * PD + p] = (bf16)yv;
      }
    }
  }
  __syncthreads();
  // ---- wB[n][s] = w_s * B_s[n], hi/lo into Gh/Gl (reuse buffers)
  #pragma unroll
  for (int i = 0; i < 2; i++) {
    int cc = tid + i * 256;
    int n = cc >> 3, s8 = (cc & 7) * 8;
    bf16x8 vh, vl;
    #pragma unroll
    for (int q = 0; q < 8; q++) {
      int s = s8 + q;
      float wb = (float)Bs[s][n ^ (s & 56)] * wsA[s];
      vh[q] = (bf16)wb;
      vl[q] = (bf16)(wb - (float)vh[q]);
    }
    *(bf16x8*)&Gh[n][s8] = vh;
    *(bf16x8*)&Gl[n][s8] = vl;
  }
  __syncthreads();
  // ---- S[p][n] = sum_s x_s[p] * wB[n][s]; write Sc
  f32x4 sacc[2][2] = {};
  #pragma unroll
  for (int ks = 0; ks < 64; ks += 32) {
    bf16x8 ax[2], bh[2], bl[2];
    #pragma unroll
    for (int i = 0; i < 2; i++) {
      int P = wt + i * 16 + lm;
      ax[i] = *(bf16x8*)&Xt[P][(ks + lk) ^ (P & 56)];
    }
    #pragma unroll
    for (int j = 0; j < 2; j++) {
      bh[j] = *(bf16x8*)&Gh[wq + j * 16 + lm][ks + lk];
      bl[j] = *(bf16x8*)&Gl[wq + j * 16 + lm][ks + lk];
    }
    #pragma unroll
    for (int i = 0; i < 2; i++)
      #pragma unroll
      for (int j = 0; j < 2; j++) {
        sacc[i][j] = __builtin_amdgcn_mfma_f32_16x16x32_bf16(ax[i], bh[j], sacc[i][j], 0, 0, 0);
        sacc[i][j] = __builtin_amdgcn_mfma_f32_16x16x32_bf16(ax[i], bl[j], sacc[i][j], 0, 0, 0);
      }
  }
  bf16* scp = Sc + ((((size_t)b * NCHUNK + c) * NH + h) << 12);
  #pragma unroll
  for (int i = 0; i < 2; i++) {
    #pragma unroll
    for (int j = 0; j < 2; j++) {
      int n = wq + j * 16 + cl;
      #pragma unroll
      for (int r = 0; r < 4; r++) {
        int p = wt + i * 16 + rw4 + r;
        scp[p * 64 + n] = (bf16)sacc[i][j][r];
      }
    }
  }
}

// ---------------------------------------------------------------- scan pass 2 (element-parallel, round-8 form)
// 2048 blocks; each thread owns one (p,n) element of one (b,h) and walks the
// 32 chunks serially: o_c = H; H = Atot[c]*H + S_c. High TLP hides latency.
__global__ __launch_bounds__(256) void state_scan_kernel(
    bf16* __restrict__ Sc, const float* __restrict__ Atot) {
  __shared__ float At[NCHUNK];
  int bid = blockIdx.x;
  int seg = bid & 15, rem = bid >> 4;          // rem = b*64 + h
  int e = seg * 256 + threadIdx.x;             // element in [0,4096)
  if (threadIdx.x < NCHUNK) At[threadIdx.x] = Atot[(rem << 5) + threadIdx.x];
  __syncthreads();
  int h = rem & 63, b = rem >> 6;
  bf16* p = Sc + ((((size_t)b * NCHUNK) * NH + h) << 12) + e;
  const size_t cstride = (size_t)NH << 12;
  float H = 0.f;
  #pragma unroll 4
  for (int c = 0; c < NCHUNK; ++c) {
    float s = (float)*p;
    *p = (bf16)H;                              // h_prev for chunk c
    H = At[c] * H + s;
    p += cstride;
  }
}

// ---------------------------------------------------------------- scan pass 3 (MFMA)
__global__ __launch_bounds__(256) void y_inter_mfma(
    bf16* __restrict__ xc, const float* __restrict__ dtH,
    const float* __restrict__ A_log, const bf16* __restrict__ Sc) {
  __shared__ bf16 Cs[64][72];
  __shared__ bf16 Hs[64][72];
  __shared__ float dts[64];
  __shared__ float eA[64];
  int bi = blockIdx.x;
  int h = bi & 63, c = (bi >> 6) & 31, b = bi >> 11;
  int tid = threadIdx.x;
  int wave = tid >> 6, lane = tid & 63;
  int lm = lane & 15, lk = (lane >> 4) * 8;
  int cl = lane & 15, rw4 = (lane >> 4) * 4;
  int wt = (wave >> 1) * 32, wp = (wave & 1) * 32;
  size_t rowbase = (size_t)b * L_ + c * 64;
  float aA = expf(A_log[h]);
  const bf16* scp = Sc + ((((size_t)b * NCHUNK + c) * NH + h) << 12);
  #pragma unroll
  for (int i = 0; i < 2; i++) {
    int cc = tid + i * 256;
    int s = cc >> 3, e8 = (cc & 7) * 8;
    bf16x8 cv = *(const bf16x8*)(xc + (rowbase + s) * CONV_ + DI_ + NST + e8);
    *(bf16x8*)&Cs[s][e8] = cv;
  }
  {
    int p = tid >> 2, n16 = (tid & 3) * 16;
    *(bf16x8*)&Hs[p][n16]     = *(const bf16x8*)(scp + p * 64 + n16);
    *(bf16x8*)&Hs[p][n16 + 8] = *(const bf16x8*)(scp + p * 64 + n16 + 8);
  }
  if (tid < 64) dts[tid] = dtH[(size_t)h * BL_ + rowbase + tid];
  __syncthreads();
  if (tid < 64) {
    float v = dts[tid];
    #pragma unroll
    for (int off = 1; off < 64; off <<= 1) {
      float o = __shfl_up(v, off, 64);
      if (tid >= off) v += o;
    }
    eA[tid] = expf(-aA * v);
  }
  __syncthreads();
  f32x4 acc[2][2] = {};
  #pragma unroll
  for (int ks = 0; ks < 64; ks += 32) {
    bf16x8 af[2], bfr[2];
    #pragma unroll
    for (int i = 0; i < 2; i++) af[i]  = *(bf16x8*)&Cs[wt + i * 16 + lm][ks + lk];
    #pragma unroll
    for (int j = 0; j < 2; j++) bfr[j] = *(bf16x8*)&Hs[wp + j * 16 + lm][ks + lk];
    #pragma unroll
    for (int i = 0; i < 2; i++)
      #pragma unroll
      for (int j = 0; j < 2; j++)
        acc[i][j] = __builtin_amdgcn_mfma_f32_16x16x32_bf16(af[i], bfr[j], acc[i][j], 0, 0, 0);
  }
  #pragma unroll
  for (int i = 0; i < 2; i++) {
    #pragma unroll
    for (int j = 0; j < 2; j++) {
      int p = wp + j * 16 + cl;
      #pragma unroll
      for (int r = 0; r < 4; r++) {
        int t = wt + i * 16 + rw4 + r;
        size_t gi = (rowbase + t) * CONV_ + h * PD + p;
        xc[gi] = (bf16)((float)xc[gi] + eA[t] * acc[i][j][r]);
      }
    }
  }
}

// ---------------------------------------------------------------- gated RMSNorm
__global__ __launch_bounds__(256) void gated_norm_kernel(
    const bf16* __restrict__ xc, bf16* __restrict__ zbuf,
    const float* __restrict__ nw) {
  int t = blockIdx.x;
  int base = threadIdx.x * 16;
  const bf16* yr = xc + (size_t)t * CONV_;
  bf16* zr = zbuf + (size_t)t * DI_;
  float tv[16], ss = 0.f;
  #pragma unroll
  for (int i8 = 0; i8 < 2; i8++) {
    bf16x8 yv = *(const bf16x8*)(yr + base + i8 * 8);
    bf16x8 zv = *(const bf16x8*)(zr + base + i8 * 8);
    #pragma unroll
    for (int q = 0; q < 8; q++) {
      float tt = (float)yv[q] * silu_f((float)zv[q]);
      tv[i8 * 8 + q] = tt;
      ss += tt * tt;
    }
  }
  ss = block_reduce_sum_256(ss);
  float r = rsqrtf(ss / (float)DI_ + EPS_);
  #pragma unroll
  for (int i8 = 0; i8 < 2; i8++) {
    f32x4 w0 = *(const f32x4*)(nw + base + i8 * 8);
    f32x4 w1 = *(const f32x4*)(nw + base + i8 * 8 + 4);
    bf16x8 o;
    #pragma unroll
    for (int q = 0; q < 4; q++) {
      o[q]     = (bf16)(w0[q] * tv[i8 * 8 + q] * r);
      o[4 + q] = (bf16)(w1[q] * tv[i8 * 8 + 4 + q] * r);
    }
    *(bf16x8*)(zr + base + i8 * 8) = o;
  }
}

// ---------------------------------------------------------------- ws diagnostic
__global__ void ws_report_kernel(float* out, float ws_mb) {
  if (blockIdx.x == 0 && threadIdx.x == 0) out[0] = ws_mb;
}

// ---------------------------------------------------------------- launch
extern "C" void kernel_launch(void* const* d_in, const int* in_sizes, int n_in,
                              void* d_out, int out_size, void* d_ws, size_t ws_size,
                              hipStream_t stream) {
  const float* u        = (const float*)d_in[0];
  const float* ln_w     = (const float*)d_in[1];
  const float* in_proj  = (const float*)d_in[2];
  const float* conv_w   = (const float*)d_in[3];
  const float* conv_b   = (const float*)d_in[4];
  const float* dt_bias  = (const float*)d_in[5];
  const float* A_log    = (const float*)d_in[6];
  const float* Dp       = (const float*)d_in[7];
  const float* norm_w   = (const float*)d_in[8];
  const float* out_proj = (const float*)d_in[9];
  float* out = (float*)d_out;

  bf16* hs = (bf16*)d_out;     // scratch inside d_out (dead before final GEMM)

  char* ws = (char*)d_ws;
  size_t off = 0;
  auto alloc = [&](size_t bytes) { char* p = ws + off; off = (off + bytes + 255) & ~(size_t)255; return p; };
  float* dtH  = (float*)alloc((size_t)BL_ * NH * 4);          //  1.05 MB  [h][b*L+t]
  float* Atot = (float*)alloc((size_t)B_ * NH * NCHUNK * 4);  //  16 KB
  bf16*  wbuf = (bf16*)alloc((size_t)4352 * DM_ * 2);         // 17.8 MB bf16 weight slice
  bf16*  shbuf= (bf16*)alloc((size_t)BL_ * XBCD_ * 2);        // 35.1 MB (xbcdt → zbuf)
  bf16*  xc   = (bf16*)alloc((size_t)BL_ * CONV_ * 2);        // 34.6 MB
  bf16*  Sc   = (bf16*)alloc((size_t)B_ * NCHUNK * NH * 64 * 64 * 2);  // 32 MB
  size_t need = off;                                          // ~120.6 MB

  if (ws_size < need) {
    ws_report_kernel<<<1, 64, 0, stream>>>(out, (float)(ws_size >> 20));
    return;
  }

  bf16* xbcdt = shbuf;          // phase 1: BL x XBCD_  (live through scan pass 1)
  bf16* zbuf  = shbuf;          // phase 3: BL x DI_

  rmsnorm_in_kernel<<<BL_, 256, 0, stream>>>(u, ln_w, hs);

  // GEMM1: zxbcdt tail (xBC + dt), weights padded to 4352 rows.
  {
    long nsrc = (long)XBCD_ * DM_, ndst = (long)4352 * DM_;
    convert_w_kernel<<<(int)(ndst / 8 / 256), 256, 0, stream>>>(
        in_proj + (size_t)DI_ * DM_, wbuf, nsrc, ndst);
    gemm_nt_sb<false><<<dim3(4352 / 128, BL_ / 128), 256, 0, stream>>>(
        hs, DM_, wbuf, DM_, xbcdt, XBCD_, nullptr, XBCD_, DM_);
  }
  convdt_kernel<<<(BL_ * 16 + BL_ * NH + 255) / 256, 256, 0, stream>>>(
      xbcdt, conv_w, conv_b, xc, dt_bias, dtH);
  atot_kernel<<<(B_ * NH * NCHUNK + 255) / 256, 256, 0, stream>>>(
      dtH, A_log, Atot);
  // chunked SSD scan with fused x-conv (xbcdt still live)
  scan_chunk_mfma<<<B_ * NH * NCHUNK, 256, 0, stream>>>(
      xc, xbcdt, conv_w, conv_b, dtH, A_log, Dp, Sc);
  state_scan_kernel<<<B_ * NH * 16, 256, 0, stream>>>(Sc, Atot);
  y_inter_mfma<<<B_ * NH * NCHUNK, 256, 0, stream>>>(xc, dtH, A_log, Sc);

  // GEMM2: z part of in_proj (xbcdt dead; shbuf becomes zbuf)
  {
    long n = (long)DI_ * DM_;
    convert_w_kernel<<<(int)(n / 8 / 256), 256, 0, stream>>>(in_proj, wbuf, n, n);
    gemm_nt_sb<false><<<dim3(DI_ / 128, BL_ / 128), 256, 0, stream>>>(
        hs, DM_, wbuf, DM_, zbuf, DI_, nullptr, DI_, DM_);
  }
  gated_norm_kernel<<<BL_, 256, 0, stream>>>(xc, zbuf, norm_w);

  // GEMM3: out projection + residual
  {
    long n = (long)DM_ * DI_;
    convert_w_kernel<<<(int)(n / 8 / 256), 256, 0, stream>>>(out_proj, wbuf, n, n);
    gemm_nt_sb<true><<<dim3(DM_ / 128, BL_ / 128), 256, 0, stream>>>(
        zbuf, DI_, wbuf, DI_, out, DM_, u, DM_, DI_);
  }
}

// Round 14
// 541.377 us; speedup vs baseline: 2.2522x; 1.0318x over previous
//
#include <hip/hip_runtime.h>
#include <hip/hip_bf16.h>

typedef __bf16 bf16;
typedef __bf16 bf16x8 __attribute__((ext_vector_type(8)));
typedef float f32x4 __attribute__((ext_vector_type(4)));

#define B_    2
#define L_    2048
#define DM_   2048
#define DI_   4096
#define NST   64
#define PD    64
#define NH    64
#define CONV_ 4224
#define XBCD_ 4288            // CONV_ + NH  (xBC + dt columns)
#define PROJ_ 8384
#define BL_   (B_ * L_)
#define NCHUNK 32             // L_ / 64
#define EPS_  1e-6f

#define WAITV(n) asm volatile("s_waitcnt vmcnt(" #n ")" ::: "memory")
#define BAR()    __builtin_amdgcn_s_barrier()

// ---------------------------------------------------------------- reductions
__device__ __forceinline__ float block_reduce_sum_256(float v) {
  #pragma unroll
  for (int m = 32; m; m >>= 1) v += __shfl_xor(v, m, 64);
  __shared__ float sred[4];
  int w = threadIdx.x >> 6;
  if ((threadIdx.x & 63) == 0) sred[w] = v;
  __syncthreads();
  return sred[0] + sred[1] + sred[2] + sred[3];
}

__device__ __forceinline__ float silu_f(float x) {
  return x / (1.0f + expf(-x));
}

// async global->LDS, 16B per lane. LDS dest is wave-uniform base; HW adds
// lane*16. [m97/m104 semantics]
__device__ __forceinline__ void async16(const bf16* g, bf16* l) {
  __builtin_amdgcn_global_load_lds(
      (__attribute__((address_space(1))) void*)g,
      (__attribute__((address_space(3))) void*)l, 16, 0, 0);
}

// ---------------------------------------------------------------- RMSNorm in
__global__ __launch_bounds__(256) void rmsnorm_in_kernel(
    const float* __restrict__ u, const float* __restrict__ w, bf16* __restrict__ hs) {
  int row = blockIdx.x;
  const float* x = u + (size_t)row * DM_;
  int base = threadIdx.x * 8;
  f32x4 v0 = *(const f32x4*)(x + base);
  f32x4 v1 = *(const f32x4*)(x + base + 4);
  float xv[8], ss = 0.f;
  #pragma unroll
  for (int i = 0; i < 4; i++) { xv[i] = v0[i]; xv[4 + i] = v1[i]; }
  #pragma unroll
  for (int i = 0; i < 8; i++) ss += xv[i] * xv[i];
  ss = block_reduce_sum_256(ss);
  float r = rsqrtf(ss / (float)DM_ + EPS_);
  f32x4 w0 = *(const f32x4*)(w + base);
  f32x4 w1 = *(const f32x4*)(w + base + 4);
  bf16x8 o;
  #pragma unroll
  for (int i = 0; i < 4; i++) { o[i] = (bf16)(w0[i] * xv[i] * r); o[4 + i] = (bf16)(w1[i] * xv[4 + i] * r); }
  *(bf16x8*)(hs + (size_t)row * DM_ + base) = o;
}

// ---------------------------------------------------------------- weight f32->bf16
__global__ __launch_bounds__(256) void convert_w_kernel(
    const float* __restrict__ src, bf16* __restrict__ dst,
    long n_src, long n_dst) {
  long e = ((long)blockIdx.x * 256 + threadIdx.x) * 8;
  if (e >= n_dst) return;
  bf16x8 o;
  if (e < n_src) {
    f32x4 a = *(const f32x4*)(src + e);
    f32x4 b = *(const f32x4*)(src + e + 4);
    #pragma unroll
    for (int q = 0; q < 4; q++) { o[q] = (bf16)a[q]; o[4 + q] = (bf16)b[q]; }
  } else {
    #pragma unroll
    for (int q = 0; q < 8; q++) o[q] = (bf16)0.f;
  }
  *(bf16x8*)(dst + e) = o;
}

// ---------------------------------------------------------------- NT GEMM (m97 single-buffer + swizzle)
// C[M][N] = A[M][K].W[N][K]^T, bf16 in. 128x128 tile, BK=64, 4 waves (2x2),
// 32 KB LDS -> up to 5 blocks/CU (inter-block overlap absorbs the drain,
// m114/m97). XOR slot swizzle: LDS[row][s] = G[row][s^(row&7)] via
// pre-swizzled gload source; ds_read XORs the same key -> conflict-free.
// [round-8 verbatim: best measured GEMM for these shapes, ~107 us]
template <bool OUT_F32>
__global__ __launch_bounds__(256, 4) void gemm_nt_sb(
    const bf16* __restrict__ A, int lda,
    const bf16* __restrict__ W, int ldw,
    void* __restrict__ Cout, int ldc, const float* __restrict__ resid,
    int N, int K) {
  __shared__ __align__(16) bf16 As[128 * 64];
  __shared__ __align__(16) bf16 Bs[128 * 64];
  // bijective XCD swizzle (m204)
  int nwg = gridDim.x * gridDim.y;
  int bid = blockIdx.y * gridDim.x + blockIdx.x;
  int q8 = nwg >> 3, r8 = nwg & 7;
  int xcd = bid & 7, loc = bid >> 3;
  int nb = (xcd < r8 ? xcd * (q8 + 1) : r8 * (q8 + 1) + (xcd - r8) * q8) + loc;
  int bn = nb % gridDim.x, bm = nb / gridDim.x;
  int m0 = bm * 128, n0 = bn * 128;
  int tid = threadIdx.x, wave = tid >> 6, lane = tid & 63;
  int wm = (wave >> 1) * 64, wn = (wave & 1) * 64;
  int lm = lane & 15, lk = (lane >> 4) * 8;
  int lr = lane >> 3;                  // row within 8-row chunk
  int cse = ((lane & 7) ^ lr) * 8;     // pre-swizzled source slot
  f32x4 acc[4][4] = {};

  int NT = K / 64;
  for (int t = 0; t < NT; ++t) {
    #pragma unroll
    for (int i = 0; i < 4; ++i) {
      int row = (wave * 4 + i) * 8;    // 16 chunks of 8 rows; 4 per wave
      async16(A + (size_t)(m0 + row + lr) * lda + t * 64 + cse, &As[row * 64]);
      async16(W + (size_t)(n0 + row + lr) * ldw + t * 64 + cse, &Bs[row * 64]);
    }
    WAITV(0);
    BAR();
    #pragma unroll
    for (int ks = 0; ks < 64; ks += 32) {
      bf16x8 af[4], bf[4];
      #pragma unroll
      for (int i = 0; i < 4; ++i) {
        int row = wm + i * 16 + lm;
        af[i] = *(const bf16x8*)&As[row * 64 + ((((ks + lk) >> 3) ^ (row & 7)) << 3)];
      }
      #pragma unroll
      for (int j = 0; j < 4; ++j) {
        int row = wn + j * 16 + lm;
        bf[j] = *(const bf16x8*)&Bs[row * 64 + ((((ks + lk) >> 3) ^ (row & 7)) << 3)];
      }
      #pragma unroll
      for (int i = 0; i < 4; ++i)
        #pragma unroll
        for (int j = 0; j < 4; ++j)
          acc[i][j] = __builtin_amdgcn_mfma_f32_16x16x32_bf16(af[i], bf[j], acc[i][j], 0, 0, 0);
    }
    BAR();
  }
  // ---- epilogue
  int r0 = m0 + wm + (lane >> 4) * 4;
  #pragma unroll
  for (int i = 0; i < 4; ++i) {
    #pragma unroll
    for (int j = 0; j < 4; ++j) {
      int col = n0 + wn + j * 16 + lm;
      if (col < N) {
        #pragma unroll
        for (int r = 0; r < 4; ++r) {
          int row = r0 + i * 16 + r;
          size_t idx = (size_t)row * ldc + col;
          float v = acc[i][j][r];
          if (resid) v += resid[idx];
          if (OUT_F32) ((float*)Cout)[idx] = v;
          else         ((bf16*)Cout)[idx]  = (bf16)v;
        }
      }
    }
  }
}

// ---------------------------------------------------------------- conv(B/C) + dt (merged)
// First BL_*16 tids: depthwise conv+SiLU over the 128 B/C cols.
// Remaining BL_*64 tids: softplus dt -> dtH[h][b*L+t].
__global__ __launch_bounds__(256) void convdt_kernel(
    const bf16* __restrict__ xbcdt, const float* __restrict__ cw,
    const float* __restrict__ cb, bf16* __restrict__ xc,
    const float* __restrict__ dt_bias, float* __restrict__ dtH) {
  int idx = blockIdx.x * 256 + threadIdx.x;
  if (idx < BL_ * 16) {
    int c8 = idx & 15, t = idx >> 4;
    int l = t % L_;
    int c = DI_ + c8 * 8;
    float acc[8];
    f32x4 bv0 = *(const f32x4*)(cb + c);
    f32x4 bv1 = *(const f32x4*)(cb + c + 4);
    #pragma unroll
    for (int q = 0; q < 4; q++) { acc[q] = bv0[q]; acc[4 + q] = bv1[q]; }
    #pragma unroll
    for (int k = 0; k < 4; k++) {
      int ls = l + k - 3;
      if (ls >= 0) {
        const bf16* xp = xbcdt + (size_t)(t + k - 3) * XBCD_ + c;
        bf16x8 xv = *(const bf16x8*)xp;
        f32x4 wv0 = *(const f32x4*)(cw + k * CONV_ + c);
        f32x4 wv1 = *(const f32x4*)(cw + k * CONV_ + c + 4);
        #pragma unroll
        for (int q = 0; q < 4; q++) { acc[q] += (float)xv[q] * wv0[q]; acc[4 + q] += (float)xv[4 + q] * wv1[q]; }
      }
    }
    bf16x8 o;
    #pragma unroll
    for (int q = 0; q < 8; q++) o[q] = (bf16)silu_f(acc[q]);
    *(bf16x8*)(xc + (size_t)t * CONV_ + c) = o;
  } else {
    int e = idx - BL_ * 16;
    if (e >= BL_ * NH) return;
    int h = e & 63, t = e >> 6;
    float raw = (float)xbcdt[(size_t)t * XBCD_ + CONV_ + h] + dt_bias[h];
    float v = (raw > 20.f) ? raw : log1pf(expf(raw));
    dtH[(size_t)h * BL_ + t] = v;
  }
}

// ---------------------------------------------------------------- scan pass 1 (MFMA SSD, fused x-conv)
__global__ __launch_bounds__(256) void scan_chunk_mfma(
    bf16* __restrict__ xc, const bf16* __restrict__ xbcdt,
    const float* __restrict__ cw, const float* __restrict__ cb,
    const float* __restrict__ dtH,
    const float* __restrict__ A_log, const float* __restrict__ Dp,
    bf16* __restrict__ Sc) {
  __shared__ bf16 Bs[64][72];   // B rows s, cols n   (swizzled)
  __shared__ bf16 Cs[64][72];   // C rows t, cols n   (natural)
  __shared__ bf16 Xt[64][72];   // x^T rows p, cols s (swizzled)
  __shared__ bf16 Gh[64][72];   // masked G hi  [t][s], later wB hi [n][s]
  __shared__ bf16 Gl[64][72];   // masked G lo  [t][s], later wB lo [n][s]
  __shared__ float dts[64];
  __shared__ float cum[64];
  __shared__ float wsA[64];
  int bi = blockIdx.x;
  int h = bi & 63, c = (bi >> 6) & 31, b = bi >> 11;
  int tid = threadIdx.x;
  int wave = tid >> 6, lane = tid & 63;
  int lm = lane & 15, lk = (lane >> 4) * 8;
  int cl = lane & 15, rw4 = (lane >> 4) * 4;
  int wt = (wave >> 1) * 32, wq = (wave & 1) * 32;
  size_t rowbase = (size_t)b * L_ + c * 64;
  float aA = expf(A_log[h]);
  // ---- stage: x via fused conv (registers), B (swizzled), C (natural)
  #pragma unroll
  for (int i = 0; i < 2; i++) {
    int cc = tid + i * 256;
    int s = cc >> 3, e8 = (cc & 7) * 8;
    const bf16* base = xc + (rowbase + s) * CONV_;
    bf16x8 bv = *(const bf16x8*)(base + DI_ + e8);
    bf16x8 cv = *(const bf16x8*)(base + DI_ + NST + e8);
    *(bf16x8*)&Bs[s][e8 ^ (s & 56)] = bv;
    *(bf16x8*)&Cs[s][e8] = cv;
    // fused depthwise conv + SiLU for x columns h*PD + e8 .. +7
    int col = h * PD + e8;
    int l = c * 64 + s;
    float acc[8];
    f32x4 cb0 = *(const f32x4*)(cb + col);
    f32x4 cb1 = *(const f32x4*)(cb + col + 4);
    #pragma unroll
    for (int q = 0; q < 4; q++) { acc[q] = cb0[q]; acc[4 + q] = cb1[q]; }
    #pragma unroll
    for (int k = 0; k < 4; k++) {
      int ls = l + k - 3;
      if (ls >= 0) {
        const bf16* xp = xbcdt + (rowbase + s + k - 3) * XBCD_ + col;
        bf16x8 xv = *(const bf16x8*)xp;
        f32x4 wv0 = *(const f32x4*)(cw + k * CONV_ + col);
        f32x4 wv1 = *(const f32x4*)(cw + k * CONV_ + col + 4);
        #pragma unroll
        for (int q = 0; q < 4; q++) { acc[q] += (float)xv[q] * wv0[q]; acc[4 + q] += (float)xv[4 + q] * wv1[q]; }
      }
    }
    #pragma unroll
    for (int q = 0; q < 8; q++) Xt[e8 + q][s ^ e8] = (bf16)silu_f(acc[q]);
  }
  if (tid < 64) dts[tid] = dtH[(size_t)h * BL_ + rowbase + tid];
  __syncthreads();
  // ---- inclusive prefix sum of dt (wave 0)
  if (tid < 64) {
    float v = dts[tid];
    #pragma unroll
    for (int off = 1; off < 64; off <<= 1) {
      float o = __shfl_up(v, off, 64);
      if (tid >= off) v += o;
    }
    cum[tid] = v;
  }
  __syncthreads();
  if (tid < 64) wsA[tid] = expf(-aA * (cum[63] - cum[tid])) * dts[tid];
  // ---- G[t][s] = sum_n C[t][n] * B[s][n]
  f32x4 gacc[2][2] = {};
  #pragma unroll
  for (int ks = 0; ks < 64; ks += 32) {
    bf16x8 af[2], bfr[2];
    #pragma unroll
    for (int i = 0; i < 2; i++) af[i] = *(bf16x8*)&Cs[wt + i * 16 + lm][ks + lk];
    #pragma unroll
    for (int j = 0; j < 2; j++) {
      int S = wq + j * 16 + lm;
      bfr[j] = *(bf16x8*)&Bs[S][(ks + lk) ^ (S & 56)];
    }
    #pragma unroll
    for (int i = 0; i < 2; i++)
      #pragma unroll
      for (int j = 0; j < 2; j++)
        gacc[i][j] = __builtin_amdgcn_mfma_f32_16x16x32_bf16(af[i], bfr[j], gacc[i][j], 0, 0, 0);
  }
  // ---- causal decay mask, hi/lo split -> Gh/Gl [t][s]
  #pragma unroll
  for (int i = 0; i < 2; i++) {
    #pragma unroll
    for (int j = 0; j < 2; j++) {
      #pragma unroll
      for (int r = 0; r < 4; r++) {
        int t = wt + i * 16 + rw4 + r;
        int s = wq + j * 16 + cl;
        float g = 0.f;
        if (s <= t) g = gacc[i][j][r] * expf(-aA * (cum[t] - cum[s])) * dts[s];
        bf16 ghi = (bf16)g;
        Gh[t][s] = ghi;
        Gl[t][s] = (bf16)(g - (float)ghi);
      }
    }
  }
  __syncthreads();
  // ---- Y[t][p] = sum_s Gm[t][s] * x_s[p];  + D*x; write into xc x-region
  f32x4 yacc[2][2] = {};
  #pragma unroll
  for (int ks = 0; ks < 64; ks += 32) {
    bf16x8 ah[2], al[2], bx[2];
    #pragma unroll
    for (int i = 0; i < 2; i++) {
      ah[i] = *(bf16x8*)&Gh[wt + i * 16 + lm][ks + lk];
      al[i] = *(bf16x8*)&Gl[wt + i * 16 + lm][ks + lk];
    }
    #pragma unroll
    for (int j = 0; j < 2; j++) {
      int P = wq + j * 16 + lm;
      bx[j] = *(bf16x8*)&Xt[P][(ks + lk) ^ (P & 56)];
    }
    #pragma unroll
    for (int i = 0; i < 2; i++)
      #pragma unroll
      for (int j = 0; j < 2; j++) {
        yacc[i][j] = __builtin_amdgcn_mfma_f32_16x16x32_bf16(ah[i], bx[j], yacc[i][j], 0, 0, 0);
        yacc[i][j] = __builtin_amdgcn_mfma_f32_16x16x32_bf16(al[i], bx[j], yacc[i][j], 0, 0, 0);
      }
  }
  float Dv = Dp[h];
  #pragma unroll
  for (int i = 0; i < 2; i++) {
    #pragma unroll
    for (int j = 0; j < 2; j++) {
      int p = wq + j * 16 + cl;
      #pragma unroll
      for (int r = 0; r < 4; r++) {
        int t = wt + i * 16 + rw4 + r;
        float yv = yacc[i][j][r] + Dv * (float)Xt[p][t ^ (p & 56)];
        xc[(rowbase + t) * CONV_ + h * PD + p] = (bf16)yv;
      }
    }
  }
  __syncthreads();
  // ---- wB[n][s] = w_s * B_s[n], hi/lo into Gh/Gl (reuse buffers)
  #pragma unroll
  for (int i = 0; i < 2; i++) {
    int cc = tid + i * 256;
    int n = cc >> 3, s8 = (cc & 7) * 8;
    bf16x8 vh, vl;
    #pragma unroll
    for (int q = 0; q < 8; q++) {
      int s = s8 + q;
      float wb = (float)Bs[s][n ^ (s & 56)] * wsA[s];
      vh[q] = (bf16)wb;
      vl[q] = (bf16)(wb - (float)vh[q]);
    }
    *(bf16x8*)&Gh[n][s8] = vh;
    *(bf16x8*)&Gl[n][s8] = vl;
  }
  __syncthreads();
  // ---- S[p][n] = sum_s x_s[p] * wB[n][s]; write Sc
  f32x4 sacc[2][2] = {};
  #pragma unroll
  for (int ks = 0; ks < 64; ks += 32) {
    bf16x8 ax[2], bh[2], bl[2];
    #pragma unroll
    for (int i = 0; i < 2; i++) {
      int P = wt + i * 16 + lm;
      ax[i] = *(bf16x8*)&Xt[P][(ks + lk) ^ (P & 56)];
    }
    #pragma unroll
    for (int j = 0; j < 2; j++) {
      bh[j] = *(bf16x8*)&Gh[wq + j * 16 + lm][ks + lk];
      bl[j] = *(bf16x8*)&Gl[wq + j * 16 + lm][ks + lk];
    }
    #pragma unroll
    for (int i = 0; i < 2; i++)
      #pragma unroll
      for (int j = 0; j < 2; j++) {
        sacc[i][j] = __builtin_amdgcn_mfma_f32_16x16x32_bf16(ax[i], bh[j], sacc[i][j], 0, 0, 0);
        sacc[i][j] = __builtin_amdgcn_mfma_f32_16x16x32_bf16(ax[i], bl[j], sacc[i][j], 0, 0, 0);
      }
  }
  bf16* scp = Sc + ((((size_t)b * NCHUNK + c) * NH + h) << 12);
  #pragma unroll
  for (int i = 0; i < 2; i++) {
    #pragma unroll
    for (int j = 0; j < 2; j++) {
      int n = wq + j * 16 + cl;
      #pragma unroll
      for (int r = 0; r < 4; r++) {
        int p = wt + i * 16 + rw4 + r;
        scp[p * 64 + n] = (bf16)sacc[i][j][r];
      }
    }
  }
}

// ---------------------------------------------------------------- scan pass 2 (element-parallel, inline Atot)
// 2048 blocks; each thread owns one (p,n) element of one (b,h) and walks the
// 32 chunks serially: o_c = H; H = At[c]*H + S_c. At computed in-block from
// dtH (identical summation order as the old atot kernel; dtH is L2-resident).
__global__ __launch_bounds__(256) void state_scan_kernel(
    bf16* __restrict__ Sc, const float* __restrict__ dtH,
    const float* __restrict__ A_log) {
  __shared__ float At[NCHUNK];
  int bid = blockIdx.x;
  int seg = bid & 15, rem = bid >> 4;          // rem = b*64 + h
  int h = rem & 63, b = rem >> 6;
  if (threadIdx.x < NCHUNK) {
    int c = threadIdx.x;
    const float* p = dtH + (size_t)h * BL_ + b * L_ + c * 64;
    float s = 0.f;
    #pragma unroll 8
    for (int i = 0; i < 64; i++) s += p[i];
    At[c] = expf(-expf(A_log[h]) * s);
  }
  __syncthreads();
  int e = seg * 256 + threadIdx.x;             // element in [0,4096)
  bf16* p = Sc + ((((size_t)b * NCHUNK) * NH + h) << 12) + e;
  const size_t cstride = (size_t)NH << 12;
  float H = 0.f;
  #pragma unroll 4
  for (int c = 0; c < NCHUNK; ++c) {
    float s = (float)*p;
    *p = (bf16)H;                              // h_prev for chunk c
    H = At[c] * H + s;
    p += cstride;
  }
}

// ---------------------------------------------------------------- scan pass 3 (MFMA)
__global__ __launch_bounds__(256) void y_inter_mfma(
    bf16* __restrict__ xc, const float* __restrict__ dtH,
    const float* __restrict__ A_log, const bf16* __restrict__ Sc) {
  __shared__ bf16 Cs[64][72];
  __shared__ bf16 Hs[64][72];
  __shared__ float dts[64];
  __shared__ float eA[64];
  int bi = blockIdx.x;
  int h = bi & 63, c = (bi >> 6) & 31, b = bi >> 11;
  int tid = threadIdx.x;
  int wave = tid >> 6, lane = tid & 63;
  int lm = lane & 15, lk = (lane >> 4) * 8;
  int cl = lane & 15, rw4 = (lane >> 4) * 4;
  int wt = (wave >> 1) * 32, wp = (wave & 1) * 32;
  size_t rowbase = (size_t)b * L_ + c * 64;
  float aA = expf(A_log[h]);
  const bf16* scp = Sc + ((((size_t)b * NCHUNK + c) * NH + h) << 12);
  #pragma unroll
  for (int i = 0; i < 2; i++) {
    int cc = tid + i * 256;
    int s = cc >> 3, e8 = (cc & 7) * 8;
    bf16x8 cv = *(const bf16x8*)(xc + (rowbase + s) * CONV_ + DI_ + NST + e8);
    *(bf16x8*)&Cs[s][e8] = cv;
  }
  {
    int p = tid >> 2, n16 = (tid & 3) * 16;
    *(bf16x8*)&Hs[p][n16]     = *(const bf16x8*)(scp + p * 64 + n16);
    *(bf16x8*)&Hs[p][n16 + 8] = *(const bf16x8*)(scp + p * 64 + n16 + 8);
  }
  if (tid < 64) dts[tid] = dtH[(size_t)h * BL_ + rowbase + tid];
  __syncthreads();
  if (tid < 64) {
    float v = dts[tid];
    #pragma unroll
    for (int off = 1; off < 64; off <<= 1) {
      float o = __shfl_up(v, off, 64);
      if (tid >= off) v += o;
    }
    eA[tid] = expf(-aA * v);
  }
  __syncthreads();
  f32x4 acc[2][2] = {};
  #pragma unroll
  for (int ks = 0; ks < 64; ks += 32) {
    bf16x8 af[2], bfr[2];
    #pragma unroll
    for (int i = 0; i < 2; i++) af[i]  = *(bf16x8*)&Cs[wt + i * 16 + lm][ks + lk];
    #pragma unroll
    for (int j = 0; j < 2; j++) bfr[j] = *(bf16x8*)&Hs[wp + j * 16 + lm][ks + lk];
    #pragma unroll
    for (int i = 0; i < 2; i++)
      #pragma unroll
      for (int j = 0; j < 2; j++)
        acc[i][j] = __builtin_amdgcn_mfma_f32_16x16x32_bf16(af[i], bfr[j], acc[i][j], 0, 0, 0);
  }
  #pragma unroll
  for (int i = 0; i < 2; i++) {
    #pragma unroll
    for (int j = 0; j < 2; j++) {
      int p = wp + j * 16 + cl;
      #pragma unroll
      for (int r = 0; r < 4; r++) {
        int t = wt + i * 16 + rw4 + r;
        size_t gi = (rowbase + t) * CONV_ + h * PD + p;
        xc[gi] = (bf16)((float)xc[gi] + eA[t] * acc[i][j][r]);
      }
    }
  }
}

// ---------------------------------------------------------------- gated RMSNorm
__global__ __launch_bounds__(256) void gated_norm_kernel(
    const bf16* __restrict__ xc, bf16* __restrict__ zbuf,
    const float* __restrict__ nw) {
  int t = blockIdx.x;
  int base = threadIdx.x * 16;
  const bf16* yr = xc + (size_t)t * CONV_;
  bf16* zr = zbuf + (size_t)t * DI_;
  float tv[16], ss = 0.f;
  #pragma unroll
  for (int i8 = 0; i8 < 2; i8++) {
    bf16x8 yv = *(const bf16x8*)(yr + base + i8 * 8);
    bf16x8 zv = *(const bf16x8*)(zr + base + i8 * 8);
    #pragma unroll
    for (int q = 0; q < 8; q++) {
      float tt = (float)yv[q] * silu_f((float)zv[q]);
      tv[i8 * 8 + q] = tt;
      ss += tt * tt;
    }
  }
  ss = block_reduce_sum_256(ss);
  float r = rsqrtf(ss / (float)DI_ + EPS_);
  #pragma unroll
  for (int i8 = 0; i8 < 2; i8++) {
    f32x4 w0 = *(const f32x4*)(nw + base + i8 * 8);
    f32x4 w1 = *(const f32x4*)(nw + base + i8 * 8 + 4);
    bf16x8 o;
    #pragma unroll
    for (int q = 0; q < 4; q++) {
      o[q]     = (bf16)(w0[q] * tv[i8 * 8 + q] * r);
      o[4 + q] = (bf16)(w1[q] * tv[i8 * 8 + 4 + q] * r);
    }
    *(bf16x8*)(zr + base + i8 * 8) = o;
  }
}

// ---------------------------------------------------------------- ws diagnostic
__global__ void ws_report_kernel(float* out, float ws_mb) {
  if (blockIdx.x == 0 && threadIdx.x == 0) out[0] = ws_mb;
}

// ---------------------------------------------------------------- launch
extern "C" void kernel_launch(void* const* d_in, const int* in_sizes, int n_in,
                              void* d_out, int out_size, void* d_ws, size_t ws_size,
                              hipStream_t stream) {
  const float* u        = (const float*)d_in[0];
  const float* ln_w     = (const float*)d_in[1];
  const float* in_proj  = (const float*)d_in[2];
  const float* conv_w   = (const float*)d_in[3];
  const float* conv_b   = (const float*)d_in[4];
  const float* dt_bias  = (const float*)d_in[5];
  const float* A_log    = (const float*)d_in[6];
  const float* Dp       = (const float*)d_in[7];
  const float* norm_w   = (const float*)d_in[8];
  const float* out_proj = (const float*)d_in[9];
  float* out = (float*)d_out;

  bf16* hs = (bf16*)d_out;     // scratch inside d_out (dead before final GEMM)

  char* ws = (char*)d_ws;
  size_t off = 0;
  auto alloc = [&](size_t bytes) { char* p = ws + off; off = (off + bytes + 255) & ~(size_t)255; return p; };
  float* dtH  = (float*)alloc((size_t)BL_ * NH * 4);          //  1.05 MB  [h][b*L+t]
  bf16*  wbuf = (bf16*)alloc((size_t)4352 * DM_ * 2);         // 17.8 MB bf16 weight slice
  bf16*  shbuf= (bf16*)alloc((size_t)BL_ * XBCD_ * 2);        // 35.1 MB (xbcdt → zbuf)
  bf16*  xc   = (bf16*)alloc((size_t)BL_ * CONV_ * 2);        // 34.6 MB
  bf16*  Sc   = (bf16*)alloc((size_t)B_ * NCHUNK * NH * 64 * 64 * 2);  // 32 MB
  size_t need = off;                                          // ~120.6 MB

  if (ws_size < need) {
    ws_report_kernel<<<1, 64, 0, stream>>>(out, (float)(ws_size >> 20));
    return;
  }

  bf16* xbcdt = shbuf;          // phase 1: BL x XBCD_  (live through scan pass 1)
  bf16* zbuf  = shbuf;          // phase 3: BL x DI_

  rmsnorm_in_kernel<<<BL_, 256, 0, stream>>>(u, ln_w, hs);

  // GEMM1: zxbcdt tail (xBC + dt), weights padded to 4352 rows.
  {
    long nsrc = (long)XBCD_ * DM_, ndst = (long)4352 * DM_;
    convert_w_kernel<<<(int)(ndst / 8 / 256), 256, 0, stream>>>(
        in_proj + (size_t)DI_ * DM_, wbuf, nsrc, ndst);
    gemm_nt_sb<false><<<dim3(4352 / 128, BL_ / 128), 256, 0, stream>>>(
        hs, DM_, wbuf, DM_, xbcdt, XBCD_, nullptr, XBCD_, DM_);
  }
  convdt_kernel<<<(BL_ * 16 + BL_ * NH + 255) / 256, 256, 0, stream>>>(
      xbcdt, conv_w, conv_b, xc, dt_bias, dtH);
  // chunked SSD scan with fused x-conv (xbcdt still live)
  scan_chunk_mfma<<<B_ * NH * NCHUNK, 256, 0, stream>>>(
      xc, xbcdt, conv_w, conv_b, dtH, A_log, Dp, Sc);
  state_scan_kernel<<<B_ * NH * 16, 256, 0, stream>>>(Sc, dtH, A_log);
  y_inter_mfma<<<B_ * NH * NCHUNK, 256, 0, stream>>>(xc, dtH, A_log, Sc);

  // GEMM2: z part of in_proj (xbcdt dead; shbuf becomes zbuf)
  {
    long n = (long)DI_ * DM_;
    convert_w_kernel<<<(int)(n / 8 / 256), 256, 0, stream>>>(in_proj, wbuf, n, n);
    gemm_nt_sb<false><<<dim3(DI_ / 128, BL_ / 128), 256, 0, stream>>>(
        hs, DM_, wbuf, DM_, zbuf, DI_, nullptr, DI_, DM_);
  }
  gated_norm_kernel<<<BL_, 256, 0, stream>>>(xc, zbuf, norm_w);

  // GEMM3: out projection + residual
  {
    long n = (long)DM_ * DI_;
    convert_w_kernel<<<(int)(n / 8 / 256), 256, 0, stream>>>(out_proj, wbuf, n, n);
    gemm_nt_sb<true><<<dim3(DM_ / 128, BL_ / 128), 256, 0, stream>>>(
        zbuf, DI_, wbuf, DI_, out, DM_, u, DM_, DI_);
  }
}